// Round 6
// baseline (420.939 us; speedup 1.0000x reference)
//
#include <hip/hip_runtime.h>
#include <math.h>

#define NNODES 50000
#define NEDGES 400000
#define ETOT   (NEDGES + NNODES)
#define NGRAPHS 64

typedef _Float16 f16;
typedef _Float16 f16x4 __attribute__((ext_vector_type(4)));
typedef _Float16 f16x8 __attribute__((ext_vector_type(8)));
typedef float f32x4 __attribute__((ext_vector_type(4)));

__device__ __forceinline__ float lrelu(float x){ return x >= 0.f ? x : 0.2f*x; }
__device__ __forceinline__ float eluf(float x){ return x > 0.f ? x : expm1f(x); }

// ---------------- CSR build (self-loop at slot 0 of each row) ----------------
__global__ void k_one(int* __restrict__ deg){
  int i = blockIdx.x*256 + threadIdx.x;
  if (i < NNODES) deg[i] = 1;
}
__global__ void k_hist(const int* __restrict__ ei, int* __restrict__ deg){
  int e = blockIdx.x*blockDim.x + threadIdx.x;
  if (e < NEDGES) atomicAdd(&deg[ei[NEDGES + e]], 1);
}
__global__ void k_scan1(const int* __restrict__ deg, int* __restrict__ part, int n){
  __shared__ int buf[256];
  int i = blockIdx.x*256 + threadIdx.x;
  buf[threadIdx.x] = (i<n)? deg[i] : 0;
  __syncthreads();
  for (int s=128; s>0; s>>=1){ if (threadIdx.x < s) buf[threadIdx.x]+=buf[threadIdx.x+s]; __syncthreads(); }
  if (threadIdx.x==0) part[blockIdx.x]=buf[0];
}
__global__ void k_scan2(const int* __restrict__ part, int* __restrict__ bpre, int* __restrict__ row_off_last, int nb){
  __shared__ int buf[256];
  int t = threadIdx.x;
  int v = (t<nb)? part[t] : 0;
  buf[t]=v; __syncthreads();
  for (int s=1;s<256;s<<=1){ int a = (t>=s)? buf[t-s]:0; __syncthreads(); buf[t]+=a; __syncthreads(); }
  if (t<nb) bpre[t] = buf[t]-v;
  if (t==255) row_off_last[0] = buf[255];
}
__global__ void k_scan3(const int* __restrict__ deg, const int* __restrict__ bpre, int* __restrict__ row_off, int n){
  __shared__ int buf[256];
  int t = threadIdx.x;
  int i = blockIdx.x*256 + t;
  int v = (i<n)? deg[i]:0;
  buf[t]=v; __syncthreads();
  for (int s=1;s<256;s<<=1){ int a=(t>=s)?buf[t-s]:0; __syncthreads(); buf[t]+=a; __syncthreads(); }
  if (i<n) row_off[i] = bpre[blockIdx.x] + buf[t]-v;
}
__global__ void k_selfpos(const int* __restrict__ row_off, int* __restrict__ csr_src,
                          int* __restrict__ csr_dst, int* __restrict__ cursor){
  int n = blockIdx.x*256 + threadIdx.x;
  if (n < NNODES){
    int p = row_off[n];
    csr_src[p] = n; csr_dst[p] = n;
    cursor[n] = 1;
  }
}
__global__ void k_scatter(const int* __restrict__ ei, const int* __restrict__ row_off,
                          int* __restrict__ cursor, int* __restrict__ csr_src, int* __restrict__ csr_dst){
  int e = blockIdx.x*blockDim.x + threadIdx.x;
  if (e < NEDGES){
    int s = ei[e], d = ei[NEDGES+e];
    int pos = row_off[d] + atomicAdd(&cursor[d],1);
    csr_src[pos] = s; csr_dst[pos] = d;
  }
}

// ---------------- weight prep ----------------
// BT1[j][k] (64x128), BT2[col][k] (256x64 per-head blocks), BT3y[j][k] (512x256, plain W3^T)
// PT* f16 [16][KF] (rows 8..15 zero)
__global__ void k_prep(const float* __restrict__ W1, const float* __restrict__ W2, const float* __restrict__ W3,
                       const float* __restrict__ as1, const float* __restrict__ ad1,
                       const float* __restrict__ as2, const float* __restrict__ ad2,
                       const float* __restrict__ as3, const float* __restrict__ ad3,
                       f16* __restrict__ BT1, f16* __restrict__ BT2, f16* __restrict__ BT3y,
                       f16* __restrict__ PT1, f16* __restrict__ PT2, f16* __restrict__ PT3){
  int u = blockIdx.x*256 + threadIdx.x;
  if (u < 8192){ int j=u>>7, k=u&127; BT1[j*128+k] = (f16)W1[(size_t)k*64+j]; return; }
  u -= 8192;
  if (u < 16384){ int col=u>>6, k=u&63; BT2[col*64+k] = (f16)W2[(size_t)k*256+col]; return; }
  u -= 16384;
  if (u < 131072){ int j=u>>8, k=u&255;
                   BT3y[(size_t)j*256+k] = (f16)W3[(size_t)k*512 + j]; return; }
  u -= 131072;
  if (u < 1024){ // PT1[o][k], layer1 block-diagonal: head h owns feats h*16..h*16+15
    int o=u>>6, k=u&63; float v=0.f;
    if (o<8){ int h=o&3; if ((k>>4)==h) v = ((o<4)?as1:ad1)[h*16 + (k&15)]; }
    PT1[u] = (f16)v; return; }
  u -= 1024;
  if (u < 1024){ // PT2[o][k] = sum_c W2[k, h*64+c] * a2_h[c]
    int o=u>>6, k=u&63; float v=0.f;
    if (o<8){ int h=o&3;
      const float* a=((o<4)?as2:ad2)+h*64; const float* w=W2+(size_t)k*256+h*64;
      for(int c=0;c<64;c++) v=fmaf(w[c],a[c],v); }
    PT2[u] = (f16)v; return; }
  u -= 1024;
  if (u < 4096){ // PT3[o][k] = sum_c W3[k, h*128+c] * a3_h[c]
    int o=u>>8, k=u&255; float v=0.f;
    if (o<8){ int h=o&3;
      const float* a=((o<4)?as3:ad3)+h*128; const float* w=W3+(size_t)k*512+h*128;
      for(int c=0;c<128;c++) v=fmaf(w[c],a[c],v); }
    PT3[u] = (f16)v; }
}

__global__ void k_cvt_x(const float* __restrict__ x, f16* __restrict__ xh){
  int u = blockIdx.x*256 + threadIdx.x;
  if (u < NNODES*32){
    float4 v = *(const float4*)&x[(size_t)u*4];
    f16x4 o; o[0]=(f16)v.x; o[1]=(f16)v.y; o[2]=(f16)v.z; o[3]=(f16)v.w;
    *(f16x4*)&xh[(size_t)u*4] = o;
  }
}

// ---------------- scores via MFMA: esd[n][0..3]=es, [4..7]=ed ----------------
template<int KF>
__global__ __launch_bounds__(256) void k_scores_m(const f16* __restrict__ g, const f16* __restrict__ PT,
                                                  float* __restrict__ esd){
  int wv = threadIdx.x>>6, lane = threadIdx.x&63;
  int r = lane&15, kb = lane>>4;
  int row0 = blockIdx.x*64 + wv*16;
  const f16* arow = g + (size_t)(row0+r)*KF + kb*8;
  const f16* brow = PT + (size_t)r*KF + kb*8;
  f32x4 acc = {0,0,0,0};
  #pragma unroll
  for (int k0=0;k0<KF;k0+=32){
    f16x8 af = *(const f16x8*)(arow + k0);
    f16x8 bf = *(const f16x8*)(brow + k0);
    acc = __builtin_amdgcn_mfma_f32_16x16x32_f16(af, bf, acc, 0,0,0);
  }
  if (r < 8){
    #pragma unroll
    for (int i=0;i<4;i++){
      int row = row0 + kb*4 + i;
      if (row < NNODES) esd[(size_t)row*8 + r] = acc[i];
    }
  }
}

// ---------------- edge-parallel softmax numerators: alphaW[p][h] ----------------
__global__ __launch_bounds__(256) void k_expw(const float* __restrict__ esd, const int* __restrict__ csr_src,
                                              const int* __restrict__ csr_dst, float* __restrict__ alphaW){
  int p = blockIdx.x*256 + threadIdx.x;
  if (p >= ETOT) return;
  int s = csr_src[p], d = csr_dst[p];
  float4 a = *(const float4*)&esd[(size_t)s*8];
  float4 b = *(const float4*)&esd[(size_t)d*8+4];
  float4 r;
  r.x = expf(lrelu(a.x+b.x));
  r.y = expf(lrelu(a.y+b.y));
  r.z = expf(lrelu(a.z+b.z));
  r.w = expf(lrelu(a.w+b.w));
  *(float4*)&alphaW[(size_t)p*4] = r;
}

// ---------------- MFMA GEMMs ----------------
// l1: h1[50000,64] = xh[50000,128] @ BT1^T ; raw (no bias/act)
__global__ __launch_bounds__(256) void k_mfma_l1(const f16* __restrict__ xh, const f16* __restrict__ BT1,
                                                 f16* __restrict__ h1h){
  int wv = threadIdx.x>>6, lane = threadIdx.x&63;
  int r = lane&15, kb = lane>>4;
  int row0 = blockIdx.x*64 + wv*16;
  const f16* arow = xh + (size_t)(row0 + r)*128 + kb*8;
  f32x4 acc[4] = {{0,0,0,0},{0,0,0,0},{0,0,0,0},{0,0,0,0}};
  for (int k0=0;k0<128;k0+=32){
    f16x8 af = *(const f16x8*)(arow + k0);
    #pragma unroll
    for (int c=0;c<4;c++){
      f16x8 bf = *(const f16x8*)(BT1 + (size_t)(c*16+r)*128 + k0 + kb*8);
      acc[c] = __builtin_amdgcn_mfma_f32_16x16x32_f16(af, bf, acc[c], 0,0,0);
    }
  }
  #pragma unroll
  for (int c=0;c<4;c++)
    #pragma unroll
    for (int i=0;i<4;i++){
      int row = row0 + kb*4 + i;
      if (row < NNODES) h1h[(size_t)row*64 + c*16 + r] = (f16)acc[c][i];
    }
}

// l2 (per-head): g2[n, h*64+j] = ELU(agg2[n, h*64+:] @ W2_h + b2)
__global__ __launch_bounds__(256) void k_mfma_l2(const f16* __restrict__ agg2h, const f16* __restrict__ BT2,
                                                 const float* __restrict__ b2, f16* __restrict__ g2h){
  int wv = threadIdx.x>>6, lane = threadIdx.x&63;
  int r = lane&15, kb = lane>>4;
  int h = blockIdx.y;
  int row0 = blockIdx.x*64 + wv*16;
  const f16* arow = agg2h + (size_t)(row0 + r)*256 + h*64 + kb*8;
  f32x4 acc[4] = {{0,0,0,0},{0,0,0,0},{0,0,0,0},{0,0,0,0}};
  #pragma unroll
  for (int k0=0;k0<64;k0+=32){
    f16x8 af = *(const f16x8*)(arow + k0);
    #pragma unroll
    for (int c=0;c<4;c++){
      f16x8 bf = *(const f16x8*)(BT2 + (size_t)(h*64+c*16+r)*64 + k0 + kb*8);
      acc[c] = __builtin_amdgcn_mfma_f32_16x16x32_f16(af, bf, acc[c], 0,0,0);
    }
  }
  #pragma unroll
  for (int c=0;c<4;c++){
    int col = h*64 + c*16 + r;
    float bb = b2[col];
    #pragma unroll
    for (int i=0;i<4;i++){
      int row = row0 + kb*4 + i;
      if (row < NNODES) g2h[(size_t)row*256 + col] = (f16)eluf(acc[c][i] + bb);
    }
  }
}

// y3[50000,512] = g2h[50000,256] @ W3 (raw, f16 out). grid (391, 8): 128 rows x 64 cols per block.
__global__ __launch_bounds__(256) void k_mfma_y3(const f16* __restrict__ g2h, const f16* __restrict__ BT3y,
                                                 f16* __restrict__ y3){
  int wv = threadIdx.x>>6, lane = threadIdx.x&63;
  int r = lane&15, kb = lane>>4;
  int row0 = blockIdx.x*128 + wv*32;
  int col0 = blockIdx.y*64;
  const f16* a0 = g2h + (size_t)(row0 + r)*256 + kb*8;
  const f16* a1 = a0 + (size_t)16*256;
  f32x4 acc[2][4];
  #pragma unroll
  for (int rt=0;rt<2;rt++)
    #pragma unroll
    for (int c=0;c<4;c++) acc[rt][c] = (f32x4){0,0,0,0};
  for (int k0=0;k0<256;k0+=32){
    f16x8 af0 = *(const f16x8*)(a0 + k0);
    f16x8 af1 = *(const f16x8*)(a1 + k0);
    #pragma unroll
    for (int c=0;c<4;c++){
      f16x8 bf = *(const f16x8*)(BT3y + (size_t)(col0+c*16+r)*256 + k0 + kb*8);
      acc[0][c] = __builtin_amdgcn_mfma_f32_16x16x32_f16(af0, bf, acc[0][c], 0,0,0);
      acc[1][c] = __builtin_amdgcn_mfma_f32_16x16x32_f16(af1, bf, acc[1][c], 0,0,0);
    }
  }
  #pragma unroll
  for (int rt=0;rt<2;rt++)
    #pragma unroll
    for (int c=0;c<4;c++){
      int col = col0 + c*16 + r;
      #pragma unroll
      for (int i=0;i<4;i++){
        int row = row0 + rt*16 + kb*4 + i;
        if (row < NNODES) y3[(size_t)row*512 + col] = (f16)acc[rt][c][i];
      }
    }
}

// ---------------- gathers: pure FMA on precomputed alphaW ----------------
__global__ __launch_bounds__(256) void k_gat1f(const f16* __restrict__ h1h, const float* __restrict__ alphaW,
    const int* __restrict__ row_off, const int* __restrict__ csr_src,
    const float* __restrict__ b1, f16* __restrict__ g1h){
  int n = blockIdx.x*4 + (threadIdx.x>>6);
  if (n >= NNODES) return;
  int t = threadIdx.x & 63;
  int head = t >> 4;
  int pos = row_off[n], end = row_off[n+1];
  float acc = 0.f, den = 0.f;
  for (; pos+1 < end; pos += 2){
    int s0 = csr_src[pos], s1 = csr_src[pos+1];
    float w0 = alphaW[(size_t)pos*4 + head];
    float w1 = alphaW[(size_t)(pos+1)*4 + head];
    float v0 = (float)h1h[(size_t)s0*64 + t];
    float v1 = (float)h1h[(size_t)s1*64 + t];
    acc = fmaf(w0, v0, fmaf(w1, v1, acc));
    den += w0 + w1;
  }
  if (pos < end){
    int s0 = csr_src[pos];
    float w0 = alphaW[(size_t)pos*4 + head];
    acc = fmaf(w0, (float)h1h[(size_t)s0*64 + t], acc);
    den += w0;
  }
  g1h[(size_t)n*64 + t] = (f16)eluf(acc/(den + 1e-16f) + b1[t]);
}

__global__ __launch_bounds__(256) void k_agg2f(const f16* __restrict__ g1h, const float* __restrict__ alphaW,
    const int* __restrict__ row_off, const int* __restrict__ csr_src,
    f16* __restrict__ agg2h){
  int n = blockIdx.x*4 + (threadIdx.x>>6);
  if (n >= NNODES) return;
  int t = threadIdx.x & 63;
  int pos = row_off[n], end = row_off[n+1];
  float c0=0.f,c1=0.f,c2=0.f,c3=0.f,d0=0.f,d1=0.f,d2=0.f,d3=0.f;
  for (; pos+1 < end; pos += 2){
    int s0 = csr_src[pos], s1 = csr_src[pos+1];
    float4 a = *(const float4*)&alphaW[(size_t)pos*4];
    float4 b = *(const float4*)&alphaW[(size_t)(pos+1)*4];
    float v0 = (float)g1h[(size_t)s0*64 + t];
    float v1 = (float)g1h[(size_t)s1*64 + t];
    c0=fmaf(a.x,v0,fmaf(b.x,v1,c0)); c1=fmaf(a.y,v0,fmaf(b.y,v1,c1));
    c2=fmaf(a.z,v0,fmaf(b.z,v1,c2)); c3=fmaf(a.w,v0,fmaf(b.w,v1,c3));
    d0+=a.x+b.x; d1+=a.y+b.y; d2+=a.z+b.z; d3+=a.w+b.w;
  }
  if (pos < end){
    int s0 = csr_src[pos];
    float4 a = *(const float4*)&alphaW[(size_t)pos*4];
    float v0 = (float)g1h[(size_t)s0*64 + t];
    c0=fmaf(a.x,v0,c0); c1=fmaf(a.y,v0,c1); c2=fmaf(a.z,v0,c2); c3=fmaf(a.w,v0,c3);
    d0+=a.x; d1+=a.y; d2+=a.z; d3+=a.w;
  }
  size_t base = (size_t)n*256;
  agg2h[base       + t] = (f16)(c0/(d0+1e-16f));
  agg2h[base +  64 + t] = (f16)(c1/(d1+1e-16f));
  agg2h[base + 128 + t] = (f16)(c2/(d2+1e-16f));
  agg2h[base + 192 + t] = (f16)(c3/(d3+1e-16f));
}

// layer3 gather on y3: out[n,c] = ELU(0.25 * sum_h (sum_e a_eh y3[src][h*128+c]) / den_h + b3[c])
// lane l owns channels c = (l&15)*8..+7 for head h = l>>4; head-mean via shfl_xor(16,32).
__global__ __launch_bounds__(256) void k_agg3y(const f16* __restrict__ y3, const float* __restrict__ alphaW,
    const int* __restrict__ row_off, const int* __restrict__ csr_src,
    const float* __restrict__ b3, float* __restrict__ g3){
  int n = blockIdx.x*4 + (threadIdx.x>>6);
  if (n >= NNODES) return;
  int lane = threadIdx.x & 63;
  int head = lane >> 4;
  int coff = lane*8;          // = head*128 + (lane&15)*8
  int pos = row_off[n], end = row_off[n+1];
  float acc[8] = {};
  float den = 0.f;
  for (; pos+1 < end; pos += 2){
    int s0 = csr_src[pos], s1 = csr_src[pos+1];
    float w0 = alphaW[(size_t)pos*4 + head];
    float w1 = alphaW[(size_t)(pos+1)*4 + head];
    f16x8 u0 = *(const f16x8*)&y3[(size_t)s0*512 + coff];
    f16x8 u1 = *(const f16x8*)&y3[(size_t)s1*512 + coff];
    #pragma unroll
    for (int j=0;j<8;j++)
      acc[j] = fmaf(w0, (float)u0[j], fmaf(w1, (float)u1[j], acc[j]));
    den += w0 + w1;
  }
  if (pos < end){
    int s0 = csr_src[pos];
    float w0 = alphaW[(size_t)pos*4 + head];
    f16x8 u0 = *(const f16x8*)&y3[(size_t)s0*512 + coff];
    #pragma unroll
    for (int j=0;j<8;j++)
      acc[j] = fmaf(w0, (float)u0[j], acc[j]);
    den += w0;
  }
  float inv = 1.f/(den + 1e-16f);
  #pragma unroll
  for (int j=0;j<8;j++){
    float r = acc[j]*inv;
    r += __shfl_xor(r, 16, 64);
    r += __shfl_xor(r, 32, 64);
    acc[j] = r;
  }
  if (lane < 16){
    int c0 = lane*8;
    #pragma unroll
    for (int j=0;j<8;j++)
      g3[(size_t)n*128 + c0 + j] = eluf(0.25f*acc[j] + b3[c0+j]);
  }
}

// ---------------- pooling + linear head ----------------
__device__ __forceinline__ int lowerb(const int* a, int n, int v){
  int lo=0, hi=n;
  while (lo<hi){ int mid=(lo+hi)>>1; if (a[mid]<v) lo=mid+1; else hi=mid; }
  return lo;
}
__global__ void k_pool8(const float* __restrict__ g3, const int* __restrict__ batch, float* __restrict__ pooledS){
  int g = blockIdx.x, ch = blockIdx.y, c = threadIdx.x; // 64 x 8 blocks, 128 threads
  int lo = lowerb(batch, NNODES, g);
  int hi = lowerb(batch, NNODES, g+1);
  int len = hi - lo;
  int b0 = lo + (len*ch)/8, b1 = lo + (len*(ch+1))/8;
  float s = 0.f;
  for (int nn=b0; nn<b1; ++nn) s += g3[(size_t)nn*128 + c];
  if (b1 > b0) atomicAdd(&pooledS[g*128+c], s);
}
__global__ void k_lin(const float* __restrict__ pooledS, const int* __restrict__ batch,
                      const float* __restrict__ Wlin, const float* __restrict__ blin, float* __restrict__ out){
  int t = threadIdx.x;
  if (t < 640){
    int g = t/10, j = t%10;
    int lo = lowerb(batch, NNODES, g);
    int hi = lowerb(batch, NNODES, g+1);
    float inv = 1.f / fmaxf((float)(hi-lo), 1.f);
    float s = blin[j];
    for (int c=0;c<128;c++) s = fmaf(pooledS[g*128+c]*inv, Wlin[c*10+j], s);
    out[t] = s;
  }
}

extern "C" void kernel_launch(void* const* d_in, const int* in_sizes, int n_in,
                              void* d_out, int out_size, void* d_ws, size_t ws_size,
                              hipStream_t stream){
  (void)in_sizes; (void)n_in; (void)out_size; (void)ws_size;
  const float* x    = (const float*)d_in[0];
  const int*   ei   = (const int*)d_in[1];
  const int*   batch= (const int*)d_in[2];
  const float* W1   = (const float*)d_in[3];
  const float* as1  = (const float*)d_in[4];
  const float* ad1  = (const float*)d_in[5];
  const float* b1   = (const float*)d_in[6];
  const float* W2   = (const float*)d_in[7];
  const float* as2  = (const float*)d_in[8];
  const float* ad2  = (const float*)d_in[9];
  const float* b2   = (const float*)d_in[10];
  const float* W3   = (const float*)d_in[11];
  const float* as3  = (const float*)d_in[12];
  const float* ad3  = (const float*)d_in[13];
  const float* b3   = (const float*)d_in[14];
  const float* Wlin = (const float*)d_in[15];
  const float* blin = (const float*)d_in[16];
  float* out = (float*)d_out;

  char* ws = (char*)d_ws;
  size_t off = 0;
  auto alloc = [&](size_t bytes)->char*{ char* p = ws + off; off += (bytes + 255) & ~(size_t)255; return p; };
  int* csr_src = (int*)alloc((size_t)ETOT*4);
  int* csr_dst = (int*)alloc((size_t)ETOT*4);
  int* row_off = (int*)alloc((size_t)(NNODES+1)*4);
  int* deg     = (int*)alloc((size_t)NNODES*4);
  int* cursor  = (int*)alloc((size_t)NNODES*4);
  int* part    = (int*)alloc(256*4);
  int* bpre    = (int*)alloc(256*4);
  float* esd   = (float*)alloc((size_t)NNODES*8*4);
  float* alphaW= (float*)alloc((size_t)ETOT*4*4);     // 7.2 MB
  f16* BT1     = (f16*)alloc(8192*2);
  f16* BT2     = (f16*)alloc(16384*2);
  f16* BT3y    = (f16*)alloc(131072*2);
  f16* PT1     = (f16*)alloc(1024*2);
  f16* PT2     = (f16*)alloc(1024*2);
  f16* PT3     = (f16*)alloc(4096*2);
  float* pooledS = (float*)alloc((size_t)NGRAPHS*128*4);
  f16* xh      = (f16*)alloc((size_t)NNODES*128*2);   // 12.8 MB
  f16* h1h     = (f16*)alloc((size_t)NNODES*64*2);    //  6.4 MB (absorbs OOB-read tails)
  f16* g1h     = (f16*)alloc((size_t)NNODES*64*2);    //  6.4 MB
  f16* agg2h   = (f16*)alloc((size_t)NNODES*256*2);   // 25.6 MB
  f16* g2h     = (f16*)alloc((size_t)NNODES*256*2);   // 25.6 MB
  f16* y3      = (f16*)alloc((size_t)NNODES*512*2);   // 51.2 MB (absorbs g2h OOB-read tail)
  float* g3    = (float*)alloc((size_t)NNODES*128*4); // 25.6 MB (absorbs y3 OOB-read tail)

  int nbE = (NEDGES+255)/256;
  int nbS = (NNODES+255)/256;
  int nbP = (ETOT+255)/256;
  int nb4 = (NNODES+3)/4;

  // CSR with self-loop at slot 0 of each row
  k_one<<<nbS,256,0,stream>>>(deg);
  k_hist<<<nbE,256,0,stream>>>(ei, deg);
  k_scan1<<<nbS,256,0,stream>>>(deg, part, NNODES);
  k_scan2<<<1,256,0,stream>>>(part, bpre, row_off+NNODES, nbS);
  k_scan3<<<nbS,256,0,stream>>>(deg, bpre, row_off, NNODES);
  k_selfpos<<<nbS,256,0,stream>>>(row_off, csr_src, csr_dst, cursor);
  k_scatter<<<nbE,256,0,stream>>>(ei, row_off, cursor, csr_src, csr_dst);

  // weight prep + x cast
  k_prep<<<632,256,0,stream>>>(W1,W2,W3,as1,ad1,as2,ad2,as3,ad3,BT1,BT2,BT3y,PT1,PT2,PT3);
  k_cvt_x<<<6250,256,0,stream>>>(x, xh);

  // layer 1
  k_mfma_l1<<<782,256,0,stream>>>(xh, BT1, h1h);
  k_scores_m<64><<<782,256,0,stream>>>(h1h, PT1, esd);
  k_expw<<<nbP,256,0,stream>>>(esd, csr_src, csr_dst, alphaW);
  k_gat1f<<<nb4,256,0,stream>>>(h1h, alphaW, row_off, csr_src, b1, g1h);

  // layer 2
  k_scores_m<64><<<782,256,0,stream>>>(g1h, PT2, esd);
  k_expw<<<nbP,256,0,stream>>>(esd, csr_src, csr_dst, alphaW);
  k_agg2f<<<nb4,256,0,stream>>>(g1h, alphaW, row_off, csr_src, agg2h);
  k_mfma_l2<<<dim3(782,4),256,0,stream>>>(agg2h, BT2, b2, g2h);

  // layer 3: GEMM first (y3 = g2 @ W3), then gather with fused den/head-mean/bias/ELU
  k_scores_m<256><<<782,256,0,stream>>>(g2h, PT3, esd);
  k_mfma_y3<<<dim3(391,8),256,0,stream>>>(g2h, BT3y, y3);
  k_expw<<<nbP,256,0,stream>>>(esd, csr_src, csr_dst, alphaW);
  k_agg3y<<<nb4,256,0,stream>>>(y3, alphaW, row_off, csr_src, b3, g3);

  // pool + linear
  hipMemsetAsync(pooledS, 0, (size_t)NGRAPHS*128*4, stream);
  k_pool8<<<dim3(NGRAPHS,8),128,0,stream>>>(g3, batch, pooledS);
  k_lin<<<1,1024,0,stream>>>(pooledS, batch, Wlin, blin, out);
}

// Round 7
// 418.974 us; speedup vs baseline: 1.0047x; 1.0047x over previous
//
#include <hip/hip_runtime.h>
#include <math.h>

#define NNODES 50000
#define NEDGES 400000
#define ETOT   (NEDGES + NNODES)
#define NGRAPHS 64

typedef _Float16 f16;
typedef _Float16 f16x4 __attribute__((ext_vector_type(4)));
typedef _Float16 f16x8 __attribute__((ext_vector_type(8)));
typedef float f32x4 __attribute__((ext_vector_type(4)));

__device__ __forceinline__ float lrelu(float x){ return x >= 0.f ? x : 0.2f*x; }
__device__ __forceinline__ float eluf(float x){ return x > 0.f ? x : expm1f(x); }

// ---------------- CSR build (self-loop at slot 0 of each row) ----------------
__global__ void k_one(int* __restrict__ deg){
  int i = blockIdx.x*256 + threadIdx.x;
  if (i < NNODES) deg[i] = 1;
}
__global__ void k_hist(const int* __restrict__ ei, int* __restrict__ deg){
  int e = blockIdx.x*blockDim.x + threadIdx.x;
  if (e < NEDGES) atomicAdd(&deg[ei[NEDGES + e]], 1);
}
__global__ void k_scan1(const int* __restrict__ deg, int* __restrict__ part, int n){
  __shared__ int buf[256];
  int i = blockIdx.x*256 + threadIdx.x;
  buf[threadIdx.x] = (i<n)? deg[i] : 0;
  __syncthreads();
  for (int s=128; s>0; s>>=1){ if (threadIdx.x < s) buf[threadIdx.x]+=buf[threadIdx.x+s]; __syncthreads(); }
  if (threadIdx.x==0) part[blockIdx.x]=buf[0];
}
__global__ void k_scan2(const int* __restrict__ part, int* __restrict__ bpre, int* __restrict__ row_off_last, int nb){
  __shared__ int buf[256];
  int t = threadIdx.x;
  int v = (t<nb)? part[t] : 0;
  buf[t]=v; __syncthreads();
  for (int s=1;s<256;s<<=1){ int a = (t>=s)? buf[t-s]:0; __syncthreads(); buf[t]+=a; __syncthreads(); }
  if (t<nb) bpre[t] = buf[t]-v;
  if (t==255) row_off_last[0] = buf[255];
}
__global__ void k_scan3(const int* __restrict__ deg, const int* __restrict__ bpre, int* __restrict__ row_off, int n){
  __shared__ int buf[256];
  int t = threadIdx.x;
  int i = blockIdx.x*256 + t;
  int v = (i<n)? deg[i]:0;
  buf[t]=v; __syncthreads();
  for (int s=1;s<256;s<<=1){ int a=(t>=s)?buf[t-s]:0; __syncthreads(); buf[t]+=a; __syncthreads(); }
  if (i<n) row_off[i] = bpre[blockIdx.x] + buf[t]-v;
}
__global__ void k_selfpos(const int* __restrict__ row_off, int* __restrict__ csr_src,
                          int* __restrict__ csr_dst, int* __restrict__ cursor){
  int n = blockIdx.x*256 + threadIdx.x;
  if (n < NNODES){
    int p = row_off[n];
    csr_src[p] = n; csr_dst[p] = n;
    cursor[n] = 1;
  }
}
__global__ void k_scatter(const int* __restrict__ ei, const int* __restrict__ row_off,
                          int* __restrict__ cursor, int* __restrict__ csr_src, int* __restrict__ csr_dst){
  int e = blockIdx.x*blockDim.x + threadIdx.x;
  if (e < NEDGES){
    int s = ei[e], d = ei[NEDGES+e];
    int pos = row_off[d] + atomicAdd(&cursor[d],1);
    csr_src[pos] = s; csr_dst[pos] = d;
  }
}

// ---------------- weight prep ----------------
__global__ void k_prep(const float* __restrict__ W1, const float* __restrict__ W2, const float* __restrict__ W3,
                       const float* __restrict__ as1, const float* __restrict__ ad1,
                       const float* __restrict__ as2, const float* __restrict__ ad2,
                       const float* __restrict__ as3, const float* __restrict__ ad3,
                       f16* __restrict__ BT1, f16* __restrict__ BT2, f16* __restrict__ BT3y,
                       f16* __restrict__ PT1, f16* __restrict__ PT2, f16* __restrict__ PT3){
  int u = blockIdx.x*256 + threadIdx.x;
  if (u < 8192){ int j=u>>7, k=u&127; BT1[j*128+k] = (f16)W1[(size_t)k*64+j]; return; }
  u -= 8192;
  if (u < 16384){ int col=u>>6, k=u&63; BT2[col*64+k] = (f16)W2[(size_t)k*256+col]; return; }
  u -= 16384;
  if (u < 131072){ int j=u>>8, k=u&255;
                   BT3y[(size_t)j*256+k] = (f16)W3[(size_t)k*512 + j]; return; }
  u -= 131072;
  if (u < 1024){ // PT1[o][k], layer1 block-diagonal
    int o=u>>6, k=u&63; float v=0.f;
    if (o<8){ int h=o&3; if ((k>>4)==h) v = ((o<4)?as1:ad1)[h*16 + (k&15)]; }
    PT1[u] = (f16)v; return; }
  u -= 1024;
  if (u < 1024){ // PT2[o][k]
    int o=u>>6, k=u&63; float v=0.f;
    if (o<8){ int h=o&3;
      const float* a=((o<4)?as2:ad2)+h*64; const float* w=W2+(size_t)k*256+h*64;
      for(int c=0;c<64;c++) v=fmaf(w[c],a[c],v); }
    PT2[u] = (f16)v; return; }
  u -= 1024;
  if (u < 4096){ // PT3[o][k]
    int o=u>>8, k=u&255; float v=0.f;
    if (o<8){ int h=o&3;
      const float* a=((o<4)?as3:ad3)+h*128; const float* w=W3+(size_t)k*512+h*128;
      for(int c=0;c<128;c++) v=fmaf(w[c],a[c],v); }
    PT3[u] = (f16)v; }
}

__global__ void k_cvt_x(const float* __restrict__ x, f16* __restrict__ xh){
  int u = blockIdx.x*256 + threadIdx.x;
  if (u < NNODES*32){
    float4 v = *(const float4*)&x[(size_t)u*4];
    f16x4 o; o[0]=(f16)v.x; o[1]=(f16)v.y; o[2]=(f16)v.z; o[3]=(f16)v.w;
    *(f16x4*)&xh[(size_t)u*4] = o;
  }
}

// ---------------- scores via MFMA: esd[n][0..3]=es, [4..7]=ed ----------------
template<int KF>
__global__ __launch_bounds__(256) void k_scores_m(const f16* __restrict__ g, const f16* __restrict__ PT,
                                                  float* __restrict__ esd){
  int wv = threadIdx.x>>6, lane = threadIdx.x&63;
  int r = lane&15, kb = lane>>4;
  int row0 = blockIdx.x*64 + wv*16;
  const f16* arow = g + (size_t)(row0+r)*KF + kb*8;
  const f16* brow = PT + (size_t)r*KF + kb*8;
  f32x4 acc = {0,0,0,0};
  #pragma unroll
  for (int k0=0;k0<KF;k0+=32){
    f16x8 af = *(const f16x8*)(arow + k0);
    f16x8 bf = *(const f16x8*)(brow + k0);
    acc = __builtin_amdgcn_mfma_f32_16x16x32_f16(af, bf, acc, 0,0,0);
  }
  if (r < 8){
    #pragma unroll
    for (int i=0;i<4;i++){
      int row = row0 + kb*4 + i;
      if (row < NNODES) esd[(size_t)row*8 + r] = acc[i];
    }
  }
}

// ---------------- edge-parallel softmax numerators: alphaW[p][h] ----------------
__global__ __launch_bounds__(256) void k_expw(const float* __restrict__ esd, const int* __restrict__ csr_src,
                                              const int* __restrict__ csr_dst, float* __restrict__ alphaW){
  int p = blockIdx.x*256 + threadIdx.x;
  if (p >= ETOT) return;
  int s = csr_src[p], d = csr_dst[p];
  float4 a = *(const float4*)&esd[(size_t)s*8];
  float4 b = *(const float4*)&esd[(size_t)d*8+4];
  float4 r;
  r.x = expf(lrelu(a.x+b.x));
  r.y = expf(lrelu(a.y+b.y));
  r.z = expf(lrelu(a.z+b.z));
  r.w = expf(lrelu(a.w+b.w));
  *(float4*)&alphaW[(size_t)p*4] = r;
}

// ---------------- MFMA GEMMs ----------------
// l1: h1[50000,64] = xh[50000,128] @ BT1^T
__global__ __launch_bounds__(256) void k_mfma_l1(const f16* __restrict__ xh, const f16* __restrict__ BT1,
                                                 f16* __restrict__ h1h){
  int wv = threadIdx.x>>6, lane = threadIdx.x&63;
  int r = lane&15, kb = lane>>4;
  int row0 = blockIdx.x*64 + wv*16;
  const f16* arow = xh + (size_t)(row0 + r)*128 + kb*8;
  f32x4 acc[4] = {{0,0,0,0},{0,0,0,0},{0,0,0,0},{0,0,0,0}};
  for (int k0=0;k0<128;k0+=32){
    f16x8 af = *(const f16x8*)(arow + k0);
    #pragma unroll
    for (int c=0;c<4;c++){
      f16x8 bf = *(const f16x8*)(BT1 + (size_t)(c*16+r)*128 + k0 + kb*8);
      acc[c] = __builtin_amdgcn_mfma_f32_16x16x32_f16(af, bf, acc[c], 0,0,0);
    }
  }
  #pragma unroll
  for (int c=0;c<4;c++)
    #pragma unroll
    for (int i=0;i<4;i++){
      int row = row0 + kb*4 + i;
      if (row < NNODES) h1h[(size_t)row*64 + c*16 + r] = (f16)acc[c][i];
    }
}

// l2 (per-head): g2[n, h*64+j] = ELU(agg2[n, h*64+:] @ W2_h + b2)
__global__ __launch_bounds__(256) void k_mfma_l2(const f16* __restrict__ agg2h, const f16* __restrict__ BT2,
                                                 const float* __restrict__ b2, f16* __restrict__ g2h){
  int wv = threadIdx.x>>6, lane = threadIdx.x&63;
  int r = lane&15, kb = lane>>4;
  int h = blockIdx.y;
  int row0 = blockIdx.x*64 + wv*16;
  const f16* arow = agg2h + (size_t)(row0 + r)*256 + h*64 + kb*8;
  f32x4 acc[4] = {{0,0,0,0},{0,0,0,0},{0,0,0,0},{0,0,0,0}};
  #pragma unroll
  for (int k0=0;k0<64;k0+=32){
    f16x8 af = *(const f16x8*)(arow + k0);
    #pragma unroll
    for (int c=0;c<4;c++){
      f16x8 bf = *(const f16x8*)(BT2 + (size_t)(h*64+c*16+r)*64 + k0 + kb*8);
      acc[c] = __builtin_amdgcn_mfma_f32_16x16x32_f16(af, bf, acc[c], 0,0,0);
    }
  }
  #pragma unroll
  for (int c=0;c<4;c++){
    int col = h*64 + c*16 + r;
    float bb = b2[col];
    #pragma unroll
    for (int i=0;i<4;i++){
      int row = row0 + kb*4 + i;
      if (row < NNODES) g2h[(size_t)row*256 + col] = (f16)eluf(acc[c][i] + bb);
    }
  }
}

// y3 GEMM + layer3 scores, col-fastest grid (9, 391).
//   x<8 : y3[rows, x*64 .. +63] = g2h @ BT3y
//   x==8: esd[rows] = g2h @ PT3 (single 16-col tile)
__global__ __launch_bounds__(256) void k_mfma_y3s(const f16* __restrict__ g2h, const f16* __restrict__ BT3y,
                                                  const f16* __restrict__ PT3,
                                                  f16* __restrict__ y3, float* __restrict__ esd){
  int wv = threadIdx.x>>6, lane = threadIdx.x&63;
  int r = lane&15, kb = lane>>4;
  int row0 = blockIdx.y*128 + wv*32;
  const f16* a0 = g2h + (size_t)(row0 + r)*256 + kb*8;
  const f16* a1 = a0 + (size_t)16*256;
  if (blockIdx.x == 8){
    // scores tile
    f32x4 acc[2] = {{0,0,0,0},{0,0,0,0}};
    const f16* brow = PT3 + (size_t)r*256 + kb*8;
    for (int k0=0;k0<256;k0+=32){
      f16x8 bf = *(const f16x8*)(brow + k0);
      acc[0] = __builtin_amdgcn_mfma_f32_16x16x32_f16(*(const f16x8*)(a0 + k0), bf, acc[0], 0,0,0);
      acc[1] = __builtin_amdgcn_mfma_f32_16x16x32_f16(*(const f16x8*)(a1 + k0), bf, acc[1], 0,0,0);
    }
    if (r < 8){
      #pragma unroll
      for (int rt=0;rt<2;rt++)
        #pragma unroll
        for (int i=0;i<4;i++){
          int row = row0 + rt*16 + kb*4 + i;
          if (row < NNODES) esd[(size_t)row*8 + r] = acc[rt][i];
        }
    }
    return;
  }
  int col0 = blockIdx.x*64;
  f32x4 acc[2][4];
  #pragma unroll
  for (int rt=0;rt<2;rt++)
    #pragma unroll
    for (int c=0;c<4;c++) acc[rt][c] = (f32x4){0,0,0,0};
  for (int k0=0;k0<256;k0+=32){
    f16x8 af0 = *(const f16x8*)(a0 + k0);
    f16x8 af1 = *(const f16x8*)(a1 + k0);
    #pragma unroll
    for (int c=0;c<4;c++){
      f16x8 bf = *(const f16x8*)(BT3y + (size_t)(col0+c*16+r)*256 + k0 + kb*8);
      acc[0][c] = __builtin_amdgcn_mfma_f32_16x16x32_f16(af0, bf, acc[0][c], 0,0,0);
      acc[1][c] = __builtin_amdgcn_mfma_f32_16x16x32_f16(af1, bf, acc[1][c], 0,0,0);
    }
  }
  #pragma unroll
  for (int rt=0;rt<2;rt++)
    #pragma unroll
    for (int c=0;c<4;c++){
      int col = col0 + c*16 + r;
      #pragma unroll
      for (int i=0;i<4;i++){
        int row = row0 + rt*16 + kb*4 + i;
        if (row < NNODES) y3[(size_t)row*512 + col] = (f16)acc[rt][c][i];
      }
    }
}

// ---------------- gathers: pure FMA on precomputed alphaW ----------------
__global__ __launch_bounds__(256) void k_gat1f(const f16* __restrict__ h1h, const float* __restrict__ alphaW,
    const int* __restrict__ row_off, const int* __restrict__ csr_src,
    const float* __restrict__ b1, f16* __restrict__ g1h){
  int n = blockIdx.x*4 + (threadIdx.x>>6);
  if (n >= NNODES) return;
  int t = threadIdx.x & 63;
  int head = t >> 4;
  int pos = row_off[n], end = row_off[n+1];
  float acc = 0.f, den = 0.f;
  for (; pos+1 < end; pos += 2){
    int s0 = csr_src[pos], s1 = csr_src[pos+1];
    float w0 = alphaW[(size_t)pos*4 + head];
    float w1 = alphaW[(size_t)(pos+1)*4 + head];
    float v0 = (float)h1h[(size_t)s0*64 + t];
    float v1 = (float)h1h[(size_t)s1*64 + t];
    acc = fmaf(w0, v0, fmaf(w1, v1, acc));
    den += w0 + w1;
  }
  if (pos < end){
    int s0 = csr_src[pos];
    float w0 = alphaW[(size_t)pos*4 + head];
    acc = fmaf(w0, (float)h1h[(size_t)s0*64 + t], acc);
    den += w0;
  }
  g1h[(size_t)n*64 + t] = (f16)eluf(acc/(den + 1e-16f) + b1[t]);
}

__global__ __launch_bounds__(256) void k_agg2f(const f16* __restrict__ g1h, const float* __restrict__ alphaW,
    const int* __restrict__ row_off, const int* __restrict__ csr_src,
    f16* __restrict__ agg2h){
  int n = blockIdx.x*4 + (threadIdx.x>>6);
  if (n >= NNODES) return;
  int t = threadIdx.x & 63;
  int pos = row_off[n], end = row_off[n+1];
  float c0=0.f,c1=0.f,c2=0.f,c3=0.f,d0=0.f,d1=0.f,d2=0.f,d3=0.f;
  for (; pos+1 < end; pos += 2){
    int s0 = csr_src[pos], s1 = csr_src[pos+1];
    float4 a = *(const float4*)&alphaW[(size_t)pos*4];
    float4 b = *(const float4*)&alphaW[(size_t)(pos+1)*4];
    float v0 = (float)g1h[(size_t)s0*64 + t];
    float v1 = (float)g1h[(size_t)s1*64 + t];
    c0=fmaf(a.x,v0,fmaf(b.x,v1,c0)); c1=fmaf(a.y,v0,fmaf(b.y,v1,c1));
    c2=fmaf(a.z,v0,fmaf(b.z,v1,c2)); c3=fmaf(a.w,v0,fmaf(b.w,v1,c3));
    d0+=a.x+b.x; d1+=a.y+b.y; d2+=a.z+b.z; d3+=a.w+b.w;
  }
  if (pos < end){
    int s0 = csr_src[pos];
    float4 a = *(const float4*)&alphaW[(size_t)pos*4];
    float v0 = (float)g1h[(size_t)s0*64 + t];
    c0=fmaf(a.x,v0,c0); c1=fmaf(a.y,v0,c1); c2=fmaf(a.z,v0,c2); c3=fmaf(a.w,v0,c3);
    d0+=a.x; d1+=a.y; d2+=a.z; d3+=a.w;
  }
  size_t base = (size_t)n*256;
  agg2h[base       + t] = (f16)(c0/(d0+1e-16f));
  agg2h[base +  64 + t] = (f16)(c1/(d1+1e-16f));
  agg2h[base + 128 + t] = (f16)(c2/(d2+1e-16f));
  agg2h[base + 192 + t] = (f16)(c3/(d3+1e-16f));
}

// layer3 gather on y3 with fused den/head-mean/bias/ELU
__global__ __launch_bounds__(256) void k_agg3y(const f16* __restrict__ y3, const float* __restrict__ alphaW,
    const int* __restrict__ row_off, const int* __restrict__ csr_src,
    const float* __restrict__ b3, float* __restrict__ g3){
  int n = blockIdx.x*4 + (threadIdx.x>>6);
  if (n >= NNODES) return;
  int lane = threadIdx.x & 63;
  int head = lane >> 4;
  int coff = lane*8;          // = head*128 + (lane&15)*8
  int pos = row_off[n], end = row_off[n+1];
  float acc[8] = {};
  float den = 0.f;
  for (; pos+1 < end; pos += 2){
    int s0 = csr_src[pos], s1 = csr_src[pos+1];
    float w0 = alphaW[(size_t)pos*4 + head];
    float w1 = alphaW[(size_t)(pos+1)*4 + head];
    f16x8 u0 = *(const f16x8*)&y3[(size_t)s0*512 + coff];
    f16x8 u1 = *(const f16x8*)&y3[(size_t)s1*512 + coff];
    #pragma unroll
    for (int j=0;j<8;j++)
      acc[j] = fmaf(w0, (float)u0[j], fmaf(w1, (float)u1[j], acc[j]));
    den += w0 + w1;
  }
  if (pos < end){
    int s0 = csr_src[pos];
    float w0 = alphaW[(size_t)pos*4 + head];
    f16x8 u0 = *(const f16x8*)&y3[(size_t)s0*512 + coff];
    #pragma unroll
    for (int j=0;j<8;j++)
      acc[j] = fmaf(w0, (float)u0[j], acc[j]);
    den += w0;
  }
  float inv = 1.f/(den + 1e-16f);
  #pragma unroll
  for (int j=0;j<8;j++){
    float r = acc[j]*inv;
    r += __shfl_xor(r, 16, 64);
    r += __shfl_xor(r, 32, 64);
    acc[j] = r;
  }
  if (lane < 16){
    int c0 = lane*8;
    #pragma unroll
    for (int j=0;j<8;j++)
      g3[(size_t)n*128 + c0 + j] = eluf(0.25f*acc[j] + b3[c0+j]);
  }
}

// ---------------- pooling + linear head ----------------
__device__ __forceinline__ int lowerb(const int* a, int n, int v){
  int lo=0, hi=n;
  while (lo<hi){ int mid=(lo+hi)>>1; if (a[mid]<v) lo=mid+1; else hi=mid; }
  return lo;
}
__global__ void k_pool8(const float* __restrict__ g3, const int* __restrict__ batch, float* __restrict__ pooledS){
  int g = blockIdx.x, ch = blockIdx.y, c = threadIdx.x;
  int lo = lowerb(batch, NNODES, g);
  int hi = lowerb(batch, NNODES, g+1);
  int len = hi - lo;
  int b0 = lo + (len*ch)/8, b1 = lo + (len*(ch+1))/8;
  float s = 0.f;
  for (int nn=b0; nn<b1; ++nn) s += g3[(size_t)nn*128 + c];
  if (b1 > b0) atomicAdd(&pooledS[g*128+c], s);
}
__global__ void k_lin(const float* __restrict__ pooledS, const int* __restrict__ batch,
                      const float* __restrict__ Wlin, const float* __restrict__ blin, float* __restrict__ out){
  int t = threadIdx.x;
  if (t < 640){
    int g = t/10, j = t%10;
    int lo = lowerb(batch, NNODES, g);
    int hi = lowerb(batch, NNODES, g+1);
    float inv = 1.f / fmaxf((float)(hi-lo), 1.f);
    float s = blin[j];
    for (int c=0;c<128;c++) s = fmaf(pooledS[g*128+c]*inv, Wlin[c*10+j], s);
    out[t] = s;
  }
}

extern "C" void kernel_launch(void* const* d_in, const int* in_sizes, int n_in,
                              void* d_out, int out_size, void* d_ws, size_t ws_size,
                              hipStream_t stream){
  (void)in_sizes; (void)n_in; (void)out_size; (void)ws_size;
  const float* x    = (const float*)d_in[0];
  const int*   ei   = (const int*)d_in[1];
  const int*   batch= (const int*)d_in[2];
  const float* W1   = (const float*)d_in[3];
  const float* as1  = (const float*)d_in[4];
  const float* ad1  = (const float*)d_in[5];
  const float* b1   = (const float*)d_in[6];
  const float* W2   = (const float*)d_in[7];
  const float* as2  = (const float*)d_in[8];
  const float* ad2  = (const float*)d_in[9];
  const float* b2   = (const float*)d_in[10];
  const float* W3   = (const float*)d_in[11];
  const float* as3  = (const float*)d_in[12];
  const float* ad3  = (const float*)d_in[13];
  const float* b3   = (const float*)d_in[14];
  const float* Wlin = (const float*)d_in[15];
  const float* blin = (const float*)d_in[16];
  float* out = (float*)d_out;

  char* ws = (char*)d_ws;
  size_t off = 0;
  auto alloc = [&](size_t bytes)->char*{ char* p = ws + off; off += (bytes + 255) & ~(size_t)255; return p; };
  int* csr_src = (int*)alloc((size_t)ETOT*4);
  int* csr_dst = (int*)alloc((size_t)ETOT*4);
  int* row_off = (int*)alloc((size_t)(NNODES+1)*4);
  int* deg     = (int*)alloc((size_t)NNODES*4);
  int* cursor  = (int*)alloc((size_t)NNODES*4);
  int* part    = (int*)alloc(256*4);
  int* bpre    = (int*)alloc(256*4);
  float* esd   = (float*)alloc((size_t)NNODES*8*4);
  float* alphaW= (float*)alloc((size_t)ETOT*4*4);
  f16* BT1     = (f16*)alloc(8192*2);
  f16* BT2     = (f16*)alloc(16384*2);
  f16* BT3y    = (f16*)alloc(131072*2);
  f16* PT1     = (f16*)alloc(1024*2);
  f16* PT2     = (f16*)alloc(1024*2);
  f16* PT3     = (f16*)alloc(4096*2);
  float* pooledS = (float*)alloc((size_t)NGRAPHS*128*4);
  f16* xh      = (f16*)alloc((size_t)NNODES*128*2);
  f16* h1h     = (f16*)alloc((size_t)NNODES*64*2);
  f16* g1h     = (f16*)alloc((size_t)NNODES*64*2);
  f16* agg2h   = (f16*)alloc((size_t)NNODES*256*2);
  f16* g2h     = (f16*)alloc((size_t)NNODES*256*2);
  f16* y3      = (f16*)alloc((size_t)NNODES*512*2);
  float* g3    = (float*)alloc((size_t)NNODES*128*4);

  int nbE = (NEDGES+255)/256;
  int nbS = (NNODES+255)/256;
  int nbP = (ETOT+255)/256;
  int nb4 = (NNODES+3)/4;

  // CSR with self-loop at slot 0 of each row
  k_one<<<nbS,256,0,stream>>>(deg);
  k_hist<<<nbE,256,0,stream>>>(ei, deg);
  k_scan1<<<nbS,256,0,stream>>>(deg, part, NNODES);
  k_scan2<<<1,256,0,stream>>>(part, bpre, row_off+NNODES, nbS);
  k_scan3<<<nbS,256,0,stream>>>(deg, bpre, row_off, NNODES);
  k_selfpos<<<nbS,256,0,stream>>>(row_off, csr_src, csr_dst, cursor);
  k_scatter<<<nbE,256,0,stream>>>(ei, row_off, cursor, csr_src, csr_dst);

  // weight prep + x cast
  k_prep<<<632,256,0,stream>>>(W1,W2,W3,as1,ad1,as2,ad2,as3,ad3,BT1,BT2,BT3y,PT1,PT2,PT3);
  k_cvt_x<<<6250,256,0,stream>>>(x, xh);

  // layer 1
  k_mfma_l1<<<782,256,0,stream>>>(xh, BT1, h1h);
  k_scores_m<64><<<782,256,0,stream>>>(h1h, PT1, esd);
  k_expw<<<nbP,256,0,stream>>>(esd, csr_src, csr_dst, alphaW);
  k_gat1f<<<nb4,256,0,stream>>>(h1h, alphaW, row_off, csr_src, b1, g1h);

  // layer 2
  k_scores_m<64><<<782,256,0,stream>>>(g1h, PT2, esd);
  k_expw<<<nbP,256,0,stream>>>(esd, csr_src, csr_dst, alphaW);
  k_agg2f<<<nb4,256,0,stream>>>(g1h, alphaW, row_off, csr_src, agg2h);
  k_mfma_l2<<<dim3(782,4),256,0,stream>>>(agg2h, BT2, b2, g2h);

  // layer 3: fused GEMM+scores (col-fastest grid), then expw, then gather
  k_mfma_y3s<<<dim3(9,391),256,0,stream>>>(g2h, BT3y, PT3, y3, esd);
  k_expw<<<nbP,256,0,stream>>>(esd, csr_src, csr_dst, alphaW);
  k_agg3y<<<nb4,256,0,stream>>>(y3, alphaW, row_off, csr_src, b3, g3);

  // pool + linear
  hipMemsetAsync(pooledS, 0, (size_t)NGRAPHS*128*4, stream);
  k_pool8<<<dim3(NGRAPHS,8),128,0,stream>>>(g3, batch, pooledS);
  k_lin<<<1,1024,0,stream>>>(pooledS, batch, Wlin, blin, out);
}

// Round 8
// 408.812 us; speedup vs baseline: 1.0297x; 1.0249x over previous
//
#include <hip/hip_runtime.h>
#include <math.h>

#define NNODES 50000
#define NEDGES 400000
#define ETOT   (NEDGES + NNODES)
#define NGRAPHS 64

typedef _Float16 f16;
typedef _Float16 f16x4 __attribute__((ext_vector_type(4)));
typedef _Float16 f16x8 __attribute__((ext_vector_type(8)));
typedef float f32x4 __attribute__((ext_vector_type(4)));

__device__ __forceinline__ float lrelu(float x){ return x >= 0.f ? x : 0.2f*x; }
__device__ __forceinline__ float eluf(float x){ return x > 0.f ? x : expm1f(x); }

// ---------------- CSR build (self-loop at slot 0 of each row) ----------------
__global__ void k_one(int* __restrict__ deg){
  int i = blockIdx.x*256 + threadIdx.x;
  if (i < NNODES) deg[i] = 1;
}
__global__ void k_hist(const int* __restrict__ ei, int* __restrict__ deg){
  int e = blockIdx.x*blockDim.x + threadIdx.x;
  if (e < NEDGES) atomicAdd(&deg[ei[NEDGES + e]], 1);
}
__global__ void k_scan1(const int* __restrict__ deg, int* __restrict__ part, int n){
  __shared__ int buf[256];
  int i = blockIdx.x*256 + threadIdx.x;
  buf[threadIdx.x] = (i<n)? deg[i] : 0;
  __syncthreads();
  for (int s=128; s>0; s>>=1){ if (threadIdx.x < s) buf[threadIdx.x]+=buf[threadIdx.x+s]; __syncthreads(); }
  if (threadIdx.x==0) part[blockIdx.x]=buf[0];
}
__global__ void k_scan2(const int* __restrict__ part, int* __restrict__ bpre, int* __restrict__ row_off_last, int nb){
  __shared__ int buf[256];
  int t = threadIdx.x;
  int v = (t<nb)? part[t] : 0;
  buf[t]=v; __syncthreads();
  for (int s=1;s<256;s<<=1){ int a = (t>=s)? buf[t-s]:0; __syncthreads(); buf[t]+=a; __syncthreads(); }
  if (t<nb) bpre[t] = buf[t]-v;
  if (t==255) row_off_last[0] = buf[255];
}
__global__ void k_scan3(const int* __restrict__ deg, const int* __restrict__ bpre, int* __restrict__ row_off, int n){
  __shared__ int buf[256];
  int t = threadIdx.x;
  int i = blockIdx.x*256 + t;
  int v = (i<n)? deg[i]:0;
  buf[t]=v; __syncthreads();
  for (int s=1;s<256;s<<=1){ int a=(t>=s)?buf[t-s]:0; __syncthreads(); buf[t]+=a; __syncthreads(); }
  if (i<n) row_off[i] = bpre[blockIdx.x] + buf[t]-v;
}
__global__ void k_selfpos(const int* __restrict__ row_off, int* __restrict__ csr_src,
                          int* __restrict__ csr_dst, int* __restrict__ cursor){
  int n = blockIdx.x*256 + threadIdx.x;
  if (n < NNODES){
    int p = row_off[n];
    csr_src[p] = n; csr_dst[p] = n;
    cursor[n] = 1;
  }
}
__global__ void k_scatter(const int* __restrict__ ei, const int* __restrict__ row_off,
                          int* __restrict__ cursor, int* __restrict__ csr_src, int* __restrict__ csr_dst){
  int e = blockIdx.x*blockDim.x + threadIdx.x;
  if (e < NEDGES){
    int s = ei[e], d = ei[NEDGES+e];
    int pos = row_off[d] + atomicAdd(&cursor[d],1);
    csr_src[pos] = s; csr_dst[pos] = d;
  }
}

// ---------------- weight prep ----------------
__global__ void k_prep(const float* __restrict__ W1, const float* __restrict__ W2, const float* __restrict__ W3,
                       const float* __restrict__ as1, const float* __restrict__ ad1,
                       const float* __restrict__ as2, const float* __restrict__ ad2,
                       const float* __restrict__ as3, const float* __restrict__ ad3,
                       f16* __restrict__ BT1, f16* __restrict__ BT2, f16* __restrict__ BT3y,
                       f16* __restrict__ PT1, f16* __restrict__ PT2, f16* __restrict__ PT3){
  int u = blockIdx.x*256 + threadIdx.x;
  if (u < 8192){ int j=u>>7, k=u&127; BT1[j*128+k] = (f16)W1[(size_t)k*64+j]; return; }
  u -= 8192;
  if (u < 16384){ int col=u>>6, k=u&63; BT2[col*64+k] = (f16)W2[(size_t)k*256+col]; return; }
  u -= 16384;
  if (u < 131072){ int j=u>>8, k=u&255;
                   BT3y[(size_t)j*256+k] = (f16)W3[(size_t)k*512 + j]; return; }
  u -= 131072;
  if (u < 1024){ // PT1[o][k], layer1 block-diagonal
    int o=u>>6, k=u&63; float v=0.f;
    if (o<8){ int h=o&3; if ((k>>4)==h) v = ((o<4)?as1:ad1)[h*16 + (k&15)]; }
    PT1[u] = (f16)v; return; }
  u -= 1024;
  if (u < 1024){ // PT2[o][k]
    int o=u>>6, k=u&63; float v=0.f;
    if (o<8){ int h=o&3;
      const float* a=((o<4)?as2:ad2)+h*64; const float* w=W2+(size_t)k*256+h*64;
      for(int c=0;c<64;c++) v=fmaf(w[c],a[c],v); }
    PT2[u] = (f16)v; return; }
  u -= 1024;
  if (u < 4096){ // PT3[o][k]
    int o=u>>8, k=u&255; float v=0.f;
    if (o<8){ int h=o&3;
      const float* a=((o<4)?as3:ad3)+h*128; const float* w=W3+(size_t)k*512+h*128;
      for(int c=0;c<128;c++) v=fmaf(w[c],a[c],v); }
    PT3[u] = (f16)v; }
}

__global__ void k_cvt_x(const float* __restrict__ x, f16* __restrict__ xh){
  int u = blockIdx.x*256 + threadIdx.x;
  if (u < NNODES*32){
    float4 v = *(const float4*)&x[(size_t)u*4];
    f16x4 o; o[0]=(f16)v.x; o[1]=(f16)v.y; o[2]=(f16)v.z; o[3]=(f16)v.w;
    *(f16x4*)&xh[(size_t)u*4] = o;
  }
}

// ---------------- scores via MFMA: esd[n][0..3]=es, [4..7]=ed ----------------
template<int KF>
__global__ __launch_bounds__(256) void k_scores_m(const f16* __restrict__ g, const f16* __restrict__ PT,
                                                  float* __restrict__ esd){
  int wv = threadIdx.x>>6, lane = threadIdx.x&63;
  int r = lane&15, kb = lane>>4;
  int row0 = blockIdx.x*64 + wv*16;
  const f16* arow = g + (size_t)(row0+r)*KF + kb*8;
  const f16* brow = PT + (size_t)r*KF + kb*8;
  f32x4 acc = {0,0,0,0};
  #pragma unroll
  for (int k0=0;k0<KF;k0+=32){
    f16x8 af = *(const f16x8*)(arow + k0);
    f16x8 bf = *(const f16x8*)(brow + k0);
    acc = __builtin_amdgcn_mfma_f32_16x16x32_f16(af, bf, acc, 0,0,0);
  }
  if (r < 8){
    #pragma unroll
    for (int i=0;i<4;i++){
      int row = row0 + kb*4 + i;
      if (row < NNODES) esd[(size_t)row*8 + r] = acc[i];
    }
  }
}

// ---------------- edge-parallel softmax numerators: alphaW[p][h] ----------------
__global__ __launch_bounds__(256) void k_expw(const float* __restrict__ esd, const int* __restrict__ csr_src,
                                              const int* __restrict__ csr_dst, float* __restrict__ alphaW){
  int p = blockIdx.x*256 + threadIdx.x;
  if (p >= ETOT) return;
  int s = csr_src[p], d = csr_dst[p];
  float4 a = *(const float4*)&esd[(size_t)s*8];
  float4 b = *(const float4*)&esd[(size_t)d*8+4];
  float4 r;
  r.x = expf(lrelu(a.x+b.x));
  r.y = expf(lrelu(a.y+b.y));
  r.z = expf(lrelu(a.z+b.z));
  r.w = expf(lrelu(a.w+b.w));
  *(float4*)&alphaW[(size_t)p*4] = r;
}

// ---------------- MFMA GEMMs ----------------
// l1: h1[50000,64] = xh[50000,128] @ BT1^T
__global__ __launch_bounds__(256) void k_mfma_l1(const f16* __restrict__ xh, const f16* __restrict__ BT1,
                                                 f16* __restrict__ h1h){
  int wv = threadIdx.x>>6, lane = threadIdx.x&63;
  int r = lane&15, kb = lane>>4;
  int row0 = blockIdx.x*64 + wv*16;
  const f16* arow = xh + (size_t)(row0 + r)*128 + kb*8;
  f32x4 acc[4] = {{0,0,0,0},{0,0,0,0},{0,0,0,0},{0,0,0,0}};
  for (int k0=0;k0<128;k0+=32){
    f16x8 af = *(const f16x8*)(arow + k0);
    #pragma unroll
    for (int c=0;c<4;c++){
      f16x8 bf = *(const f16x8*)(BT1 + (size_t)(c*16+r)*128 + k0 + kb*8);
      acc[c] = __builtin_amdgcn_mfma_f32_16x16x32_f16(af, bf, acc[c], 0,0,0);
    }
  }
  #pragma unroll
  for (int c=0;c<4;c++)
    #pragma unroll
    for (int i=0;i<4;i++){
      int row = row0 + kb*4 + i;
      if (row < NNODES) h1h[(size_t)row*64 + c*16 + r] = (f16)acc[c][i];
    }
}

// l2 (per-head): g2[n, h*64+j] = ELU(agg2[n, h*64+:] @ W2_h + b2)
__global__ __launch_bounds__(256) void k_mfma_l2(const f16* __restrict__ agg2h, const f16* __restrict__ BT2,
                                                 const float* __restrict__ b2, f16* __restrict__ g2h){
  int wv = threadIdx.x>>6, lane = threadIdx.x&63;
  int r = lane&15, kb = lane>>4;
  int h = blockIdx.y;
  int row0 = blockIdx.x*64 + wv*16;
  const f16* arow = agg2h + (size_t)(row0 + r)*256 + h*64 + kb*8;
  f32x4 acc[4] = {{0,0,0,0},{0,0,0,0},{0,0,0,0},{0,0,0,0}};
  #pragma unroll
  for (int k0=0;k0<64;k0+=32){
    f16x8 af = *(const f16x8*)(arow + k0);
    #pragma unroll
    for (int c=0;c<4;c++){
      f16x8 bf = *(const f16x8*)(BT2 + (size_t)(h*64+c*16+r)*64 + k0 + kb*8);
      acc[c] = __builtin_amdgcn_mfma_f32_16x16x32_f16(af, bf, acc[c], 0,0,0);
    }
  }
  #pragma unroll
  for (int c=0;c<4;c++){
    int col = h*64 + c*16 + r;
    float bb = b2[col];
    #pragma unroll
    for (int i=0;i<4;i++){
      int row = row0 + kb*4 + i;
      if (row < NNODES) g2h[(size_t)row*256 + col] = (f16)eluf(acc[c][i] + bb);
    }
  }
}

// y3 GEMM + layer3 scores, A-resident-in-registers. One wave owns 32 rows and
// computes ALL 512 cols + the scores tile; A fetched once, B served from L2.
__global__ __launch_bounds__(256) void k_mfma_y3r(const f16* __restrict__ g2h, const f16* __restrict__ BT3y,
                                                  const f16* __restrict__ PT3,
                                                  f16* __restrict__ y3, float* __restrict__ esd){
  int wv = threadIdx.x>>6, lane = threadIdx.x&63;
  int r = lane&15, kb = lane>>4;
  int row0 = blockIdx.x*128 + wv*32;   // 391 blocks x 4 waves x 32 rows
  const f16* a0 = g2h + (size_t)(row0 + r)*256 + kb*8;
  const f16* a1 = a0 + (size_t)16*256;
  f16x8 a[2][8];
  #pragma unroll
  for (int kk=0;kk<8;kk++){
    a[0][kk] = *(const f16x8*)(a0 + kk*32);
    a[1][kk] = *(const f16x8*)(a1 + kk*32);
  }
  for (int ct=0; ct<32; ++ct){
    const f16* brow = BT3y + (size_t)(ct*16+r)*256 + kb*8;
    f32x4 acc0 = {0,0,0,0}, acc1 = {0,0,0,0};
    #pragma unroll
    for (int kk=0;kk<8;kk++){
      f16x8 bf = *(const f16x8*)(brow + kk*32);
      acc0 = __builtin_amdgcn_mfma_f32_16x16x32_f16(a[0][kk], bf, acc0, 0,0,0);
      acc1 = __builtin_amdgcn_mfma_f32_16x16x32_f16(a[1][kk], bf, acc1, 0,0,0);
    }
    int col = ct*16 + r;
    #pragma unroll
    for (int i=0;i<4;i++){
      int row = row0 + kb*4 + i;
      if (row < NNODES) y3[(size_t)row*512 + col] = (f16)acc0[i];
      row += 16;
      if (row < NNODES) y3[(size_t)row*512 + col] = (f16)acc1[i];
    }
  }
  { // scores tile: esd = g2 @ PT3
    const f16* brow = PT3 + (size_t)r*256 + kb*8;
    f32x4 acc0 = {0,0,0,0}, acc1 = {0,0,0,0};
    #pragma unroll
    for (int kk=0;kk<8;kk++){
      f16x8 bf = *(const f16x8*)(brow + kk*32);
      acc0 = __builtin_amdgcn_mfma_f32_16x16x32_f16(a[0][kk], bf, acc0, 0,0,0);
      acc1 = __builtin_amdgcn_mfma_f32_16x16x32_f16(a[1][kk], bf, acc1, 0,0,0);
    }
    if (r < 8){
      #pragma unroll
      for (int i=0;i<4;i++){
        int row = row0 + kb*4 + i;
        if (row < NNODES) esd[(size_t)row*8 + r] = acc0[i];
        row += 16;
        if (row < NNODES) esd[(size_t)row*8 + r] = acc1[i];
      }
    }
  }
}

// ---------------- gathers: pure FMA on precomputed alphaW ----------------
__global__ __launch_bounds__(256) void k_gat1f(const f16* __restrict__ h1h, const float* __restrict__ alphaW,
    const int* __restrict__ row_off, const int* __restrict__ csr_src,
    const float* __restrict__ b1, f16* __restrict__ g1h){
  int n = blockIdx.x*4 + (threadIdx.x>>6);
  if (n >= NNODES) return;
  int t = threadIdx.x & 63;
  int head = t >> 4;
  int pos = row_off[n], end = row_off[n+1];
  float acc = 0.f, den = 0.f;
  for (; pos+1 < end; pos += 2){
    int s0 = csr_src[pos], s1 = csr_src[pos+1];
    float w0 = alphaW[(size_t)pos*4 + head];
    float w1 = alphaW[(size_t)(pos+1)*4 + head];
    float v0 = (float)h1h[(size_t)s0*64 + t];
    float v1 = (float)h1h[(size_t)s1*64 + t];
    acc = fmaf(w0, v0, fmaf(w1, v1, acc));
    den += w0 + w1;
  }
  if (pos < end){
    int s0 = csr_src[pos];
    float w0 = alphaW[(size_t)pos*4 + head];
    acc = fmaf(w0, (float)h1h[(size_t)s0*64 + t], acc);
    den += w0;
  }
  g1h[(size_t)n*64 + t] = (f16)eluf(acc/(den + 1e-16f) + b1[t]);
}

__global__ __launch_bounds__(256) void k_agg2f(const f16* __restrict__ g1h, const float* __restrict__ alphaW,
    const int* __restrict__ row_off, const int* __restrict__ csr_src,
    f16* __restrict__ agg2h){
  int n = blockIdx.x*4 + (threadIdx.x>>6);
  if (n >= NNODES) return;
  int t = threadIdx.x & 63;
  int pos = row_off[n], end = row_off[n+1];
  float c0=0.f,c1=0.f,c2=0.f,c3=0.f,d0=0.f,d1=0.f,d2=0.f,d3=0.f;
  for (; pos+1 < end; pos += 2){
    int s0 = csr_src[pos], s1 = csr_src[pos+1];
    float4 a = *(const float4*)&alphaW[(size_t)pos*4];
    float4 b = *(const float4*)&alphaW[(size_t)(pos+1)*4];
    float v0 = (float)g1h[(size_t)s0*64 + t];
    float v1 = (float)g1h[(size_t)s1*64 + t];
    c0=fmaf(a.x,v0,fmaf(b.x,v1,c0)); c1=fmaf(a.y,v0,fmaf(b.y,v1,c1));
    c2=fmaf(a.z,v0,fmaf(b.z,v1,c2)); c3=fmaf(a.w,v0,fmaf(b.w,v1,c3));
    d0+=a.x+b.x; d1+=a.y+b.y; d2+=a.z+b.z; d3+=a.w+b.w;
  }
  if (pos < end){
    int s0 = csr_src[pos];
    float4 a = *(const float4*)&alphaW[(size_t)pos*4];
    float v0 = (float)g1h[(size_t)s0*64 + t];
    c0=fmaf(a.x,v0,c0); c1=fmaf(a.y,v0,c1); c2=fmaf(a.z,v0,c2); c3=fmaf(a.w,v0,c3);
    d0+=a.x; d1+=a.y; d2+=a.z; d3+=a.w;
  }
  size_t base = (size_t)n*256;
  agg2h[base       + t] = (f16)(c0/(d0+1e-16f));
  agg2h[base +  64 + t] = (f16)(c1/(d1+1e-16f));
  agg2h[base + 128 + t] = (f16)(c2/(d2+1e-16f));
  agg2h[base + 192 + t] = (f16)(c3/(d3+1e-16f));
}

// layer3 gather on y3 with fused den/head-mean/bias/ELU
__global__ __launch_bounds__(256) void k_agg3y(const f16* __restrict__ y3, const float* __restrict__ alphaW,
    const int* __restrict__ row_off, const int* __restrict__ csr_src,
    const float* __restrict__ b3, float* __restrict__ g3){
  int n = blockIdx.x*4 + (threadIdx.x>>6);
  if (n >= NNODES) return;
  int lane = threadIdx.x & 63;
  int head = lane >> 4;
  int coff = lane*8;          // = head*128 + (lane&15)*8
  int pos = row_off[n], end = row_off[n+1];
  float acc[8] = {};
  float den = 0.f;
  for (; pos+1 < end; pos += 2){
    int s0 = csr_src[pos], s1 = csr_src[pos+1];
    float w0 = alphaW[(size_t)pos*4 + head];
    float w1 = alphaW[(size_t)(pos+1)*4 + head];
    f16x8 u0 = *(const f16x8*)&y3[(size_t)s0*512 + coff];
    f16x8 u1 = *(const f16x8*)&y3[(size_t)s1*512 + coff];
    #pragma unroll
    for (int j=0;j<8;j++)
      acc[j] = fmaf(w0, (float)u0[j], fmaf(w1, (float)u1[j], acc[j]));
    den += w0 + w1;
  }
  if (pos < end){
    int s0 = csr_src[pos];
    float w0 = alphaW[(size_t)pos*4 + head];
    f16x8 u0 = *(const f16x8*)&y3[(size_t)s0*512 + coff];
    #pragma unroll
    for (int j=0;j<8;j++)
      acc[j] = fmaf(w0, (float)u0[j], acc[j]);
    den += w0;
  }
  float inv = 1.f/(den + 1e-16f);
  #pragma unroll
  for (int j=0;j<8;j++){
    float r = acc[j]*inv;
    r += __shfl_xor(r, 16, 64);
    r += __shfl_xor(r, 32, 64);
    acc[j] = r;
  }
  if (lane < 16){
    int c0 = lane*8;
    #pragma unroll
    for (int j=0;j<8;j++)
      g3[(size_t)n*128 + c0 + j] = eluf(0.25f*acc[j] + b3[c0+j]);
  }
}

// ---------------- pooling + linear head ----------------
__device__ __forceinline__ int lowerb(const int* a, int n, int v){
  int lo=0, hi=n;
  while (lo<hi){ int mid=(lo+hi)>>1; if (a[mid]<v) lo=mid+1; else hi=mid; }
  return lo;
}
__global__ void k_pool8(const float* __restrict__ g3, const int* __restrict__ batch, float* __restrict__ pooledS){
  int g = blockIdx.x, ch = blockIdx.y, c = threadIdx.x;
  int lo = lowerb(batch, NNODES, g);
  int hi = lowerb(batch, NNODES, g+1);
  int len = hi - lo;
  int b0 = lo + (len*ch)/8, b1 = lo + (len*(ch+1))/8;
  float s = 0.f;
  for (int nn=b0; nn<b1; ++nn) s += g3[(size_t)nn*128 + c];
  if (b1 > b0) atomicAdd(&pooledS[g*128+c], s);
}
__global__ void k_lin(const float* __restrict__ pooledS, const int* __restrict__ batch,
                      const float* __restrict__ Wlin, const float* __restrict__ blin, float* __restrict__ out){
  int t = threadIdx.x;
  if (t < 640){
    int g = t/10, j = t%10;
    int lo = lowerb(batch, NNODES, g);
    int hi = lowerb(batch, NNODES, g+1);
    float inv = 1.f / fmaxf((float)(hi-lo), 1.f);
    float s = blin[j];
    for (int c=0;c<128;c++) s = fmaf(pooledS[g*128+c]*inv, Wlin[c*10+j], s);
    out[t] = s;
  }
}

extern "C" void kernel_launch(void* const* d_in, const int* in_sizes, int n_in,
                              void* d_out, int out_size, void* d_ws, size_t ws_size,
                              hipStream_t stream){
  (void)in_sizes; (void)n_in; (void)out_size; (void)ws_size;
  const float* x    = (const float*)d_in[0];
  const int*   ei   = (const int*)d_in[1];
  const int*   batch= (const int*)d_in[2];
  const float* W1   = (const float*)d_in[3];
  const float* as1  = (const float*)d_in[4];
  const float* ad1  = (const float*)d_in[5];
  const float* b1   = (const float*)d_in[6];
  const float* W2   = (const float*)d_in[7];
  const float* as2  = (const float*)d_in[8];
  const float* ad2  = (const float*)d_in[9];
  const float* b2   = (const float*)d_in[10];
  const float* W3   = (const float*)d_in[11];
  const float* as3  = (const float*)d_in[12];
  const float* ad3  = (const float*)d_in[13];
  const float* b3   = (const float*)d_in[14];
  const float* Wlin = (const float*)d_in[15];
  const float* blin = (const float*)d_in[16];
  float* out = (float*)d_out;

  char* ws = (char*)d_ws;
  size_t off = 0;
  auto alloc = [&](size_t bytes)->char*{ char* p = ws + off; off += (bytes + 255) & ~(size_t)255; return p; };
  int* csr_src = (int*)alloc((size_t)ETOT*4);
  int* csr_dst = (int*)alloc((size_t)ETOT*4);
  int* row_off = (int*)alloc((size_t)(NNODES+1)*4);
  int* deg     = (int*)alloc((size_t)NNODES*4);
  int* cursor  = (int*)alloc((size_t)NNODES*4);
  int* part    = (int*)alloc(256*4);
  int* bpre    = (int*)alloc(256*4);
  float* esd   = (float*)alloc((size_t)NNODES*8*4);
  float* alphaW= (float*)alloc((size_t)ETOT*4*4);
  f16* BT1     = (f16*)alloc(8192*2);
  f16* BT2     = (f16*)alloc(16384*2);
  f16* BT3y    = (f16*)alloc(131072*2);
  f16* PT1     = (f16*)alloc(1024*2);
  f16* PT2     = (f16*)alloc(1024*2);
  f16* PT3     = (f16*)alloc(4096*2);
  float* pooledS = (float*)alloc((size_t)NGRAPHS*128*4);
  f16* xh      = (f16*)alloc((size_t)NNODES*128*2);
  f16* h1h     = (f16*)alloc((size_t)NNODES*64*2);
  f16* g1h     = (f16*)alloc((size_t)NNODES*64*2);
  f16* agg2h   = (f16*)alloc((size_t)NNODES*256*2);
  f16* g2h     = (f16*)alloc((size_t)NNODES*256*2);
  f16* y3      = (f16*)alloc((size_t)NNODES*512*2);
  float* g3    = (float*)alloc((size_t)NNODES*128*4);

  int nbE = (NEDGES+255)/256;
  int nbS = (NNODES+255)/256;
  int nbP = (ETOT+255)/256;
  int nb4 = (NNODES+3)/4;

  // CSR with self-loop at slot 0 of each row
  k_one<<<nbS,256,0,stream>>>(deg);
  k_hist<<<nbE,256,0,stream>>>(ei, deg);
  k_scan1<<<nbS,256,0,stream>>>(deg, part, NNODES);
  k_scan2<<<1,256,0,stream>>>(part, bpre, row_off+NNODES, nbS);
  k_scan3<<<nbS,256,0,stream>>>(deg, bpre, row_off, NNODES);
  k_selfpos<<<nbS,256,0,stream>>>(row_off, csr_src, csr_dst, cursor);
  k_scatter<<<nbE,256,0,stream>>>(ei, row_off, cursor, csr_src, csr_dst);

  // weight prep + x cast
  k_prep<<<632,256,0,stream>>>(W1,W2,W3,as1,ad1,as2,ad2,as3,ad3,BT1,BT2,BT3y,PT1,PT2,PT3);
  k_cvt_x<<<6250,256,0,stream>>>(x, xh);

  // layer 1
  k_mfma_l1<<<782,256,0,stream>>>(xh, BT1, h1h);
  k_scores_m<64><<<782,256,0,stream>>>(h1h, PT1, esd);
  k_expw<<<nbP,256,0,stream>>>(esd, csr_src, csr_dst, alphaW);
  k_gat1f<<<nb4,256,0,stream>>>(h1h, alphaW, row_off, csr_src, b1, g1h);

  // layer 2
  k_scores_m<64><<<782,256,0,stream>>>(g1h, PT2, esd);
  k_expw<<<nbP,256,0,stream>>>(esd, csr_src, csr_dst, alphaW);
  k_agg2f<<<nb4,256,0,stream>>>(g1h, alphaW, row_off, csr_src, agg2h);
  k_mfma_l2<<<dim3(782,4),256,0,stream>>>(agg2h, BT2, b2, g2h);

  // layer 3: A-resident fused GEMM+scores, then expw, then gather
  k_mfma_y3r<<<391,256,0,stream>>>(g2h, BT3y, PT3, y3, esd);
  k_expw<<<nbP,256,0,stream>>>(esd, csr_src, csr_dst, alphaW);
  k_agg3y<<<nb4,256,0,stream>>>(y3, alphaW, row_off, csr_src, b3, g3);

  // pool + linear
  hipMemsetAsync(pooledS, 0, (size_t)NGRAPHS*128*4, stream);
  k_pool8<<<dim3(NGRAPHS,8),128,0,stream>>>(g3, batch, pooledS);
  k_lin<<<1,1024,0,stream>>>(pooledS, batch, Wlin, blin, out);
}

// Round 9
// 396.470 us; speedup vs baseline: 1.0617x; 1.0311x over previous
//
#include <hip/hip_runtime.h>
#include <math.h>

#define NNODES 50000
#define NEDGES 400000
#define ETOT   (NEDGES + NNODES)
#define NGRAPHS 64

typedef _Float16 f16;
typedef _Float16 f16x4 __attribute__((ext_vector_type(4)));
typedef _Float16 f16x8 __attribute__((ext_vector_type(8)));
typedef float f32x4 __attribute__((ext_vector_type(4)));

__device__ __forceinline__ float lrelu(float x){ return x >= 0.f ? x : 0.2f*x; }
__device__ __forceinline__ float eluf(float x){ return x > 0.f ? x : expm1f(x); }

// ---------------- CSR build (self-loop at slot 0 of each row) ----------------
__global__ void k_one(int* __restrict__ deg){
  int i = blockIdx.x*256 + threadIdx.x;
  if (i < NNODES) deg[i] = 1;
}
__global__ void k_hist(const int* __restrict__ ei, int* __restrict__ deg){
  int e = blockIdx.x*blockDim.x + threadIdx.x;
  if (e < NEDGES) atomicAdd(&deg[ei[NEDGES + e]], 1);
}
__global__ void k_scan1(const int* __restrict__ deg, int* __restrict__ part, int n){
  __shared__ int buf[256];
  int i = blockIdx.x*256 + threadIdx.x;
  buf[threadIdx.x] = (i<n)? deg[i] : 0;
  __syncthreads();
  for (int s=128; s>0; s>>=1){ if (threadIdx.x < s) buf[threadIdx.x]+=buf[threadIdx.x+s]; __syncthreads(); }
  if (threadIdx.x==0) part[blockIdx.x]=buf[0];
}
__global__ void k_scan2(const int* __restrict__ part, int* __restrict__ bpre, int* __restrict__ row_off_last, int nb){
  __shared__ int buf[256];
  int t = threadIdx.x;
  int v = (t<nb)? part[t] : 0;
  buf[t]=v; __syncthreads();
  for (int s=1;s<256;s<<=1){ int a = (t>=s)? buf[t-s]:0; __syncthreads(); buf[t]+=a; __syncthreads(); }
  if (t<nb) bpre[t] = buf[t]-v;
  if (t==255) row_off_last[0] = buf[255];
}
__global__ void k_scan3(const int* __restrict__ deg, const int* __restrict__ bpre, int* __restrict__ row_off, int n){
  __shared__ int buf[256];
  int t = threadIdx.x;
  int i = blockIdx.x*256 + t;
  int v = (i<n)? deg[i]:0;
  buf[t]=v; __syncthreads();
  for (int s=1;s<256;s<<=1){ int a=(t>=s)?buf[t-s]:0; __syncthreads(); buf[t]+=a; __syncthreads(); }
  if (i<n) row_off[i] = bpre[blockIdx.x] + buf[t]-v;
}
__global__ void k_selfpos(const int* __restrict__ row_off, int* __restrict__ csr_src,
                          int* __restrict__ csr_dst, int* __restrict__ cursor){
  int n = blockIdx.x*256 + threadIdx.x;
  if (n < NNODES){
    int p = row_off[n];
    csr_src[p] = n; csr_dst[p] = n;
    cursor[n] = 1;
  }
}
__global__ void k_scatter(const int* __restrict__ ei, const int* __restrict__ row_off,
                          int* __restrict__ cursor, int* __restrict__ csr_src, int* __restrict__ csr_dst){
  int e = blockIdx.x*blockDim.x + threadIdx.x;
  if (e < NEDGES){
    int s = ei[e], d = ei[NEDGES+e];
    int pos = row_off[d] + atomicAdd(&cursor[d],1);
    csr_src[pos] = s; csr_dst[pos] = d;
  }
}

// ---------------- weight prep ----------------
__global__ void k_prep(const float* __restrict__ W1, const float* __restrict__ W2, const float* __restrict__ W3,
                       const float* __restrict__ as1, const float* __restrict__ ad1,
                       const float* __restrict__ as2, const float* __restrict__ ad2,
                       const float* __restrict__ as3, const float* __restrict__ ad3,
                       f16* __restrict__ BT1, f16* __restrict__ BT2, f16* __restrict__ BT3y,
                       f16* __restrict__ PT1, f16* __restrict__ PT2, f16* __restrict__ PT3){
  int u = blockIdx.x*256 + threadIdx.x;
  if (u < 8192){ int j=u>>7, k=u&127; BT1[j*128+k] = (f16)W1[(size_t)k*64+j]; return; }
  u -= 8192;
  if (u < 16384){ int col=u>>6, k=u&63; BT2[col*64+k] = (f16)W2[(size_t)k*256+col]; return; }
  u -= 16384;
  if (u < 131072){ int j=u>>8, k=u&255;
                   BT3y[(size_t)j*256+k] = (f16)W3[(size_t)k*512 + j]; return; }
  u -= 131072;
  if (u < 1024){ // PT1[o][k], layer1 block-diagonal
    int o=u>>6, k=u&63; float v=0.f;
    if (o<8){ int h=o&3; if ((k>>4)==h) v = ((o<4)?as1:ad1)[h*16 + (k&15)]; }
    PT1[u] = (f16)v; return; }
  u -= 1024;
  if (u < 1024){ // PT2[o][k]
    int o=u>>6, k=u&63; float v=0.f;
    if (o<8){ int h=o&3;
      const float* a=((o<4)?as2:ad2)+h*64; const float* w=W2+(size_t)k*256+h*64;
      for(int c=0;c<64;c++) v=fmaf(w[c],a[c],v); }
    PT2[u] = (f16)v; return; }
  u -= 1024;
  if (u < 4096){ // PT3[o][k]
    int o=u>>8, k=u&255; float v=0.f;
    if (o<8){ int h=o&3;
      const float* a=((o<4)?as3:ad3)+h*128; const float* w=W3+(size_t)k*512+h*128;
      for(int c=0;c<128;c++) v=fmaf(w[c],a[c],v); }
    PT3[u] = (f16)v; }
}

__global__ void k_cvt_x(const float* __restrict__ x, f16* __restrict__ xh){
  int u = blockIdx.x*256 + threadIdx.x;
  if (u < NNODES*32){
    float4 v = *(const float4*)&x[(size_t)u*4];
    f16x4 o; o[0]=(f16)v.x; o[1]=(f16)v.y; o[2]=(f16)v.z; o[3]=(f16)v.w;
    *(f16x4*)&xh[(size_t)u*4] = o;
  }
}

// ---------------- scores via MFMA: esd[n][0..3]=es, [4..7]=ed ----------------
template<int KF>
__global__ __launch_bounds__(256) void k_scores_m(const f16* __restrict__ g, const f16* __restrict__ PT,
                                                  float* __restrict__ esd){
  int wv = threadIdx.x>>6, lane = threadIdx.x&63;
  int r = lane&15, kb = lane>>4;
  int row0 = blockIdx.x*64 + wv*16;
  const f16* arow = g + (size_t)(row0+r)*KF + kb*8;
  const f16* brow = PT + (size_t)r*KF + kb*8;
  f32x4 acc = {0,0,0,0};
  #pragma unroll
  for (int k0=0;k0<KF;k0+=32){
    f16x8 af = *(const f16x8*)(arow + k0);
    f16x8 bf = *(const f16x8*)(brow + k0);
    acc = __builtin_amdgcn_mfma_f32_16x16x32_f16(af, bf, acc, 0,0,0);
  }
  if (r < 8){
    #pragma unroll
    for (int i=0;i<4;i++){
      int row = row0 + kb*4 + i;
      if (row < NNODES) esd[(size_t)row*8 + r] = acc[i];
    }
  }
}

// ---------------- edge-parallel softmax numerators: alphaW[p][h] ----------------
__global__ __launch_bounds__(256) void k_expw(const float* __restrict__ esd, const int* __restrict__ csr_src,
                                              const int* __restrict__ csr_dst, float* __restrict__ alphaW){
  int p = blockIdx.x*256 + threadIdx.x;
  if (p >= ETOT) return;
  int s = csr_src[p], d = csr_dst[p];
  float4 a = *(const float4*)&esd[(size_t)s*8];
  float4 b = *(const float4*)&esd[(size_t)d*8+4];
  float4 r;
  r.x = expf(lrelu(a.x+b.x));
  r.y = expf(lrelu(a.y+b.y));
  r.z = expf(lrelu(a.z+b.z));
  r.w = expf(lrelu(a.w+b.w));
  *(float4*)&alphaW[(size_t)p*4] = r;
}

// ---------------- MFMA GEMMs ----------------
// l1: h1[50000,64] = xh[50000,128] @ BT1^T
__global__ __launch_bounds__(256) void k_mfma_l1(const f16* __restrict__ xh, const f16* __restrict__ BT1,
                                                 f16* __restrict__ h1h){
  int wv = threadIdx.x>>6, lane = threadIdx.x&63;
  int r = lane&15, kb = lane>>4;
  int row0 = blockIdx.x*64 + wv*16;
  const f16* arow = xh + (size_t)(row0 + r)*128 + kb*8;
  f32x4 acc[4] = {{0,0,0,0},{0,0,0,0},{0,0,0,0},{0,0,0,0}};
  for (int k0=0;k0<128;k0+=32){
    f16x8 af = *(const f16x8*)(arow + k0);
    #pragma unroll
    for (int c=0;c<4;c++){
      f16x8 bf = *(const f16x8*)(BT1 + (size_t)(c*16+r)*128 + k0 + kb*8);
      acc[c] = __builtin_amdgcn_mfma_f32_16x16x32_f16(af, bf, acc[c], 0,0,0);
    }
  }
  #pragma unroll
  for (int c=0;c<4;c++)
    #pragma unroll
    for (int i=0;i<4;i++){
      int row = row0 + kb*4 + i;
      if (row < NNODES) h1h[(size_t)row*64 + c*16 + r] = (f16)acc[c][i];
    }
}

// l2 (per-head): g2[n, h*64+j] = ELU(agg2[n, h*64+:] @ W2_h + b2)
__global__ __launch_bounds__(256) void k_mfma_l2(const f16* __restrict__ agg2h, const f16* __restrict__ BT2,
                                                 const float* __restrict__ b2, f16* __restrict__ g2h){
  int wv = threadIdx.x>>6, lane = threadIdx.x&63;
  int r = lane&15, kb = lane>>4;
  int h = blockIdx.y;
  int row0 = blockIdx.x*64 + wv*16;
  const f16* arow = agg2h + (size_t)(row0 + r)*256 + h*64 + kb*8;
  f32x4 acc[4] = {{0,0,0,0},{0,0,0,0},{0,0,0,0},{0,0,0,0}};
  #pragma unroll
  for (int k0=0;k0<64;k0+=32){
    f16x8 af = *(const f16x8*)(arow + k0);
    #pragma unroll
    for (int c=0;c<4;c++){
      f16x8 bf = *(const f16x8*)(BT2 + (size_t)(h*64+c*16+r)*64 + k0 + kb*8);
      acc[c] = __builtin_amdgcn_mfma_f32_16x16x32_f16(af, bf, acc[c], 0,0,0);
    }
  }
  #pragma unroll
  for (int c=0;c<4;c++){
    int col = h*64 + c*16 + r;
    float bb = b2[col];
    #pragma unroll
    for (int i=0;i<4;i++){
      int row = row0 + kb*4 + i;
      if (row < NNODES) g2h[(size_t)row*256 + col] = (f16)eluf(acc[c][i] + bb);
    }
  }
}

// y3 GEMM + layer3 scores, A-resident-in-registers.
__global__ __launch_bounds__(256) void k_mfma_y3r(const f16* __restrict__ g2h, const f16* __restrict__ BT3y,
                                                  const f16* __restrict__ PT3,
                                                  f16* __restrict__ y3, float* __restrict__ esd){
  int wv = threadIdx.x>>6, lane = threadIdx.x&63;
  int r = lane&15, kb = lane>>4;
  int row0 = blockIdx.x*128 + wv*32;
  const f16* a0 = g2h + (size_t)(row0 + r)*256 + kb*8;
  const f16* a1 = a0 + (size_t)16*256;
  f16x8 a[2][8];
  #pragma unroll
  for (int kk=0;kk<8;kk++){
    a[0][kk] = *(const f16x8*)(a0 + kk*32);
    a[1][kk] = *(const f16x8*)(a1 + kk*32);
  }
  for (int ct=0; ct<32; ++ct){
    const f16* brow = BT3y + (size_t)(ct*16+r)*256 + kb*8;
    f32x4 acc0 = {0,0,0,0}, acc1 = {0,0,0,0};
    #pragma unroll
    for (int kk=0;kk<8;kk++){
      f16x8 bf = *(const f16x8*)(brow + kk*32);
      acc0 = __builtin_amdgcn_mfma_f32_16x16x32_f16(a[0][kk], bf, acc0, 0,0,0);
      acc1 = __builtin_amdgcn_mfma_f32_16x16x32_f16(a[1][kk], bf, acc1, 0,0,0);
    }
    int col = ct*16 + r;
    #pragma unroll
    for (int i=0;i<4;i++){
      int row = row0 + kb*4 + i;
      if (row < NNODES) y3[(size_t)row*512 + col] = (f16)acc0[i];
      row += 16;
      if (row < NNODES) y3[(size_t)row*512 + col] = (f16)acc1[i];
    }
  }
  { // scores tile: esd = g2 @ PT3
    const f16* brow = PT3 + (size_t)r*256 + kb*8;
    f32x4 acc0 = {0,0,0,0}, acc1 = {0,0,0,0};
    #pragma unroll
    for (int kk=0;kk<8;kk++){
      f16x8 bf = *(const f16x8*)(brow + kk*32);
      acc0 = __builtin_amdgcn_mfma_f32_16x16x32_f16(a[0][kk], bf, acc0, 0,0,0);
      acc1 = __builtin_amdgcn_mfma_f32_16x16x32_f16(a[1][kk], bf, acc1, 0,0,0);
    }
    if (r < 8){
      #pragma unroll
      for (int i=0;i<4;i++){
        int row = row0 + kb*4 + i;
        if (row < NNODES) esd[(size_t)row*8 + r] = acc0[i];
        row += 16;
        if (row < NNODES) esd[(size_t)row*8 + r] = acc1[i];
      }
    }
  }
}

// ---------------- gathers: 4-edge software pipeline on precomputed alphaW ----------------
__global__ __launch_bounds__(256) void k_gat1f(const f16* __restrict__ h1h, const float* __restrict__ alphaW,
    const int* __restrict__ row_off, const int* __restrict__ csr_src,
    const float* __restrict__ b1, f16* __restrict__ g1h){
  int n = blockIdx.x*4 + (threadIdx.x>>6);
  if (n >= NNODES) return;
  int t = threadIdx.x & 63;
  int head = t >> 4;
  int pos = row_off[n], end = row_off[n+1];
  float acc = 0.f, den = 0.f;
  for (; pos+3 < end; pos += 4){
    int s0 = csr_src[pos], s1 = csr_src[pos+1], s2 = csr_src[pos+2], s3 = csr_src[pos+3];
    float w0 = alphaW[(size_t)pos*4 + head];
    float w1 = alphaW[(size_t)(pos+1)*4 + head];
    float w2 = alphaW[(size_t)(pos+2)*4 + head];
    float w3 = alphaW[(size_t)(pos+3)*4 + head];
    float v0 = (float)h1h[(size_t)s0*64 + t];
    float v1 = (float)h1h[(size_t)s1*64 + t];
    float v2 = (float)h1h[(size_t)s2*64 + t];
    float v3 = (float)h1h[(size_t)s3*64 + t];
    acc = fmaf(w0, v0, fmaf(w1, v1, fmaf(w2, v2, fmaf(w3, v3, acc))));
    den += (w0 + w1) + (w2 + w3);
  }
  for (; pos < end; ++pos){
    int s0 = csr_src[pos];
    float w0 = alphaW[(size_t)pos*4 + head];
    acc = fmaf(w0, (float)h1h[(size_t)s0*64 + t], acc);
    den += w0;
  }
  g1h[(size_t)n*64 + t] = (f16)eluf(acc/(den + 1e-16f) + b1[t]);
}

__global__ __launch_bounds__(256) void k_agg2f(const f16* __restrict__ g1h, const float* __restrict__ alphaW,
    const int* __restrict__ row_off, const int* __restrict__ csr_src,
    f16* __restrict__ agg2h){
  int n = blockIdx.x*4 + (threadIdx.x>>6);
  if (n >= NNODES) return;
  int t = threadIdx.x & 63;
  int pos = row_off[n], end = row_off[n+1];
  float c0=0.f,c1=0.f,c2=0.f,c3=0.f,d0=0.f,d1=0.f,d2=0.f,d3=0.f;
  for (; pos+3 < end; pos += 4){
    int s0 = csr_src[pos], s1 = csr_src[pos+1], s2 = csr_src[pos+2], s3 = csr_src[pos+3];
    float4 a = *(const float4*)&alphaW[(size_t)pos*4];
    float4 b = *(const float4*)&alphaW[(size_t)(pos+1)*4];
    float4 c = *(const float4*)&alphaW[(size_t)(pos+2)*4];
    float4 d = *(const float4*)&alphaW[(size_t)(pos+3)*4];
    float v0 = (float)g1h[(size_t)s0*64 + t];
    float v1 = (float)g1h[(size_t)s1*64 + t];
    float v2 = (float)g1h[(size_t)s2*64 + t];
    float v3 = (float)g1h[(size_t)s3*64 + t];
    c0=fmaf(a.x,v0,fmaf(b.x,v1,fmaf(c.x,v2,fmaf(d.x,v3,c0))));
    c1=fmaf(a.y,v0,fmaf(b.y,v1,fmaf(c.y,v2,fmaf(d.y,v3,c1))));
    c2=fmaf(a.z,v0,fmaf(b.z,v1,fmaf(c.z,v2,fmaf(d.z,v3,c2))));
    c3=fmaf(a.w,v0,fmaf(b.w,v1,fmaf(c.w,v2,fmaf(d.w,v3,c3))));
    d0+=(a.x+b.x)+(c.x+d.x); d1+=(a.y+b.y)+(c.y+d.y);
    d2+=(a.z+b.z)+(c.z+d.z); d3+=(a.w+b.w)+(c.w+d.w);
  }
  for (; pos < end; ++pos){
    int s0 = csr_src[pos];
    float4 a = *(const float4*)&alphaW[(size_t)pos*4];
    float v0 = (float)g1h[(size_t)s0*64 + t];
    c0=fmaf(a.x,v0,c0); c1=fmaf(a.y,v0,c1); c2=fmaf(a.z,v0,c2); c3=fmaf(a.w,v0,c3);
    d0+=a.x; d1+=a.y; d2+=a.z; d3+=a.w;
  }
  size_t base = (size_t)n*256;
  agg2h[base       + t] = (f16)(c0/(d0+1e-16f));
  agg2h[base +  64 + t] = (f16)(c1/(d1+1e-16f));
  agg2h[base + 128 + t] = (f16)(c2/(d2+1e-16f));
  agg2h[base + 192 + t] = (f16)(c3/(d3+1e-16f));
}

// layer3 gather on y3 with fused den/head-mean/bias/ELU, 4-edge pipeline
__global__ __launch_bounds__(256) void k_agg3y(const f16* __restrict__ y3, const float* __restrict__ alphaW,
    const int* __restrict__ row_off, const int* __restrict__ csr_src,
    const float* __restrict__ b3, float* __restrict__ g3){
  int n = blockIdx.x*4 + (threadIdx.x>>6);
  if (n >= NNODES) return;
  int lane = threadIdx.x & 63;
  int head = lane >> 4;
  int coff = lane*8;          // = head*128 + (lane&15)*8
  int pos = row_off[n], end = row_off[n+1];
  float acc[8] = {};
  float den = 0.f;
  for (; pos+3 < end; pos += 4){
    int s0 = csr_src[pos], s1 = csr_src[pos+1], s2 = csr_src[pos+2], s3 = csr_src[pos+3];
    float w0 = alphaW[(size_t)pos*4 + head];
    float w1 = alphaW[(size_t)(pos+1)*4 + head];
    float w2 = alphaW[(size_t)(pos+2)*4 + head];
    float w3 = alphaW[(size_t)(pos+3)*4 + head];
    f16x8 u0 = *(const f16x8*)&y3[(size_t)s0*512 + coff];
    f16x8 u1 = *(const f16x8*)&y3[(size_t)s1*512 + coff];
    f16x8 u2 = *(const f16x8*)&y3[(size_t)s2*512 + coff];
    f16x8 u3 = *(const f16x8*)&y3[(size_t)s3*512 + coff];
    #pragma unroll
    for (int j=0;j<8;j++)
      acc[j] = fmaf(w0,(float)u0[j], fmaf(w1,(float)u1[j], fmaf(w2,(float)u2[j], fmaf(w3,(float)u3[j], acc[j]))));
    den += (w0 + w1) + (w2 + w3);
  }
  for (; pos < end; ++pos){
    int s0 = csr_src[pos];
    float w0 = alphaW[(size_t)pos*4 + head];
    f16x8 u0 = *(const f16x8*)&y3[(size_t)s0*512 + coff];
    #pragma unroll
    for (int j=0;j<8;j++)
      acc[j] = fmaf(w0, (float)u0[j], acc[j]);
    den += w0;
  }
  float inv = 1.f/(den + 1e-16f);
  #pragma unroll
  for (int j=0;j<8;j++){
    float r = acc[j]*inv;
    r += __shfl_xor(r, 16, 64);
    r += __shfl_xor(r, 32, 64);
    acc[j] = r;
  }
  if (lane < 16){
    int c0 = lane*8;
    #pragma unroll
    for (int j=0;j<8;j++)
      g3[(size_t)n*128 + c0 + j] = eluf(0.25f*acc[j] + b3[c0+j]);
  }
}

// ---------------- pooling + linear head ----------------
__device__ __forceinline__ int lowerb(const int* a, int n, int v){
  int lo=0, hi=n;
  while (lo<hi){ int mid=(lo+hi)>>1; if (a[mid]<v) lo=mid+1; else hi=mid; }
  return lo;
}
__global__ void k_pool8(const float* __restrict__ g3, const int* __restrict__ batch, float* __restrict__ pooledS){
  int g = blockIdx.x, ch = blockIdx.y, c = threadIdx.x;
  int lo = lowerb(batch, NNODES, g);
  int hi = lowerb(batch, NNODES, g+1);
  int len = hi - lo;
  int b0 = lo + (len*ch)/8, b1 = lo + (len*(ch+1))/8;
  float s = 0.f;
  for (int nn=b0; nn<b1; ++nn) s += g3[(size_t)nn*128 + c];
  if (b1 > b0) atomicAdd(&pooledS[g*128+c], s);
}
__global__ void k_lin(const float* __restrict__ pooledS, const int* __restrict__ batch,
                      const float* __restrict__ Wlin, const float* __restrict__ blin, float* __restrict__ out){
  int t = threadIdx.x;
  if (t < 640){
    int g = t/10, j = t%10;
    int lo = lowerb(batch, NNODES, g);
    int hi = lowerb(batch, NNODES, g+1);
    float inv = 1.f / fmaxf((float)(hi-lo), 1.f);
    float s = blin[j];
    for (int c=0;c<128;c++) s = fmaf(pooledS[g*128+c]*inv, Wlin[c*10+j], s);
    out[t] = s;
  }
}

extern "C" void kernel_launch(void* const* d_in, const int* in_sizes, int n_in,
                              void* d_out, int out_size, void* d_ws, size_t ws_size,
                              hipStream_t stream){
  (void)in_sizes; (void)n_in; (void)out_size; (void)ws_size;
  const float* x    = (const float*)d_in[0];
  const int*   ei   = (const int*)d_in[1];
  const int*   batch= (const int*)d_in[2];
  const float* W1   = (const float*)d_in[3];
  const float* as1  = (const float*)d_in[4];
  const float* ad1  = (const float*)d_in[5];
  const float* b1   = (const float*)d_in[6];
  const float* W2   = (const float*)d_in[7];
  const float* as2  = (const float*)d_in[8];
  const float* ad2  = (const float*)d_in[9];
  const float* b2   = (const float*)d_in[10];
  const float* W3   = (const float*)d_in[11];
  const float* as3  = (const float*)d_in[12];
  const float* ad3  = (const float*)d_in[13];
  const float* b3   = (const float*)d_in[14];
  const float* Wlin = (const float*)d_in[15];
  const float* blin = (const float*)d_in[16];
  float* out = (float*)d_out;

  char* ws = (char*)d_ws;
  size_t off = 0;
  auto alloc = [&](size_t bytes)->char*{ char* p = ws + off; off += (bytes + 255) & ~(size_t)255; return p; };
  int* csr_src = (int*)alloc((size_t)ETOT*4);
  int* csr_dst = (int*)alloc((size_t)ETOT*4);
  int* row_off = (int*)alloc((size_t)(NNODES+1)*4);
  int* deg     = (int*)alloc((size_t)NNODES*4);
  int* cursor  = (int*)alloc((size_t)NNODES*4);
  int* part    = (int*)alloc(256*4);
  int* bpre    = (int*)alloc(256*4);
  float* esd   = (float*)alloc((size_t)NNODES*8*4);
  float* alphaW= (float*)alloc((size_t)ETOT*4*4);
  f16* BT1     = (f16*)alloc(8192*2);
  f16* BT2     = (f16*)alloc(16384*2);
  f16* BT3y    = (f16*)alloc(131072*2);
  f16* PT1     = (f16*)alloc(1024*2);
  f16* PT2     = (f16*)alloc(1024*2);
  f16* PT3     = (f16*)alloc(4096*2);
  float* pooledS = (float*)alloc((size_t)NGRAPHS*128*4);
  f16* xh      = (f16*)alloc((size_t)NNODES*128*2);
  f16* h1h     = (f16*)alloc((size_t)NNODES*64*2);
  f16* g1h     = (f16*)alloc((size_t)NNODES*64*2);
  f16* agg2h   = (f16*)alloc((size_t)NNODES*256*2);
  f16* g2h     = (f16*)alloc((size_t)NNODES*256*2);
  f16* y3      = (f16*)alloc((size_t)NNODES*512*2);
  float* g3    = (float*)alloc((size_t)NNODES*128*4);

  int nbE = (NEDGES+255)/256;
  int nbS = (NNODES+255)/256;
  int nbP = (ETOT+255)/256;
  int nb4 = (NNODES+3)/4;

  // CSR with self-loop at slot 0 of each row
  k_one<<<nbS,256,0,stream>>>(deg);
  k_hist<<<nbE,256,0,stream>>>(ei, deg);
  k_scan1<<<nbS,256,0,stream>>>(deg, part, NNODES);
  k_scan2<<<1,256,0,stream>>>(part, bpre, row_off+NNODES, nbS);
  k_scan3<<<nbS,256,0,stream>>>(deg, bpre, row_off, NNODES);
  k_selfpos<<<nbS,256,0,stream>>>(row_off, csr_src, csr_dst, cursor);
  k_scatter<<<nbE,256,0,stream>>>(ei, row_off, cursor, csr_src, csr_dst);

  // weight prep + x cast
  k_prep<<<632,256,0,stream>>>(W1,W2,W3,as1,ad1,as2,ad2,as3,ad3,BT1,BT2,BT3y,PT1,PT2,PT3);
  k_cvt_x<<<6250,256,0,stream>>>(x, xh);

  // layer 1
  k_mfma_l1<<<782,256,0,stream>>>(xh, BT1, h1h);
  k_scores_m<64><<<782,256,0,stream>>>(h1h, PT1, esd);
  k_expw<<<nbP,256,0,stream>>>(esd, csr_src, csr_dst, alphaW);
  k_gat1f<<<nb4,256,0,stream>>>(h1h, alphaW, row_off, csr_src, b1, g1h);

  // layer 2
  k_scores_m<64><<<782,256,0,stream>>>(g1h, PT2, esd);
  k_expw<<<nbP,256,0,stream>>>(esd, csr_src, csr_dst, alphaW);
  k_agg2f<<<nb4,256,0,stream>>>(g1h, alphaW, row_off, csr_src, agg2h);
  k_mfma_l2<<<dim3(782,4),256,0,stream>>>(agg2h, BT2, b2, g2h);

  // layer 3: A-resident fused GEMM+scores, then expw, then gather
  k_mfma_y3r<<<391,256,0,stream>>>(g2h, BT3y, PT3, y3, esd);
  k_expw<<<nbP,256,0,stream>>>(esd, csr_src, csr_dst, alphaW);
  k_agg3y<<<nb4,256,0,stream>>>(y3, alphaW, row_off, csr_src, b3, g3);

  // pool + linear
  hipMemsetAsync(pooledS, 0, (size_t)NGRAPHS*128*4, stream);
  k_pool8<<<dim3(NGRAPHS,8),128,0,stream>>>(g3, batch, pooledS);
  k_lin<<<1,1024,0,stream>>>(pooledS, batch, Wlin, blin, out);
}